// Round 1
// baseline (436.214 us; speedup 1.0000x reference)
//
#include <hip/hip_runtime.h>

#define B_ 4
#define T_ 2048
#define C_ 1024
#define H_ 16
#define HD_ 64
#define BT_ (B_*T_)            // 8192
#define C3_ (3*C_)             // 3072
#define BHTD_ ((size_t)B_*H_*T_*HD_)  // 8388608 elements per q/k/v

using u16 = unsigned short;
using u32 = unsigned int;
using bf16x8 = __attribute__((ext_vector_type(8))) short;
using f32x4  = __attribute__((ext_vector_type(4))) float;
using u16x4  = __attribute__((ext_vector_type(4))) u16;

__device__ __forceinline__ u16 f2bf(float f) {
  u32 u = __float_as_uint(f);
  u += 0x7fffu + ((u >> 16) & 1u);   // round-to-nearest-even
  return (u16)(u >> 16);
}

__device__ __forceinline__ void gload16(const void* g,
                                        __attribute__((address_space(3))) void* l) {
  __builtin_amdgcn_global_load_lds((const __attribute__((address_space(1))) void*)g,
                                   l, 16, 0, 0);
}

// ---------------- convert fp32 -> bf16 (vectorized) ----------------
__global__ __launch_bounds__(256) void k_cvt_bf16(const float* __restrict__ in,
                                                  u16* __restrict__ out) {
  size_t i = (size_t)(blockIdx.x * blockDim.x + threadIdx.x) * 4;
  f32x4 f = *(const f32x4*)(in + i);
  u16x4 o;
  o[0] = f2bf(f[0]); o[1] = f2bf(f[1]); o[2] = f2bf(f[2]); o[3] = f2bf(f[3]);
  *(u16x4*)(out + i) = o;
}

// ---------------- transpose+convert: w[K][N] f32 -> wt[N][K] bf16 ----------------
__global__ __launch_bounds__(256) void k_transpose_bf16(const float* __restrict__ w,
                                                        u16* __restrict__ wt,
                                                        int K, int N) {
  __shared__ float t[32][33];
  int n0 = blockIdx.x * 32, k0 = blockIdx.y * 32;
  int tx = threadIdx.x & 31;
  int ty = threadIdx.x >> 5;   // 0..7
  #pragma unroll
  for (int r = 0; r < 4; ++r)
    t[ty + r*8][tx] = w[(size_t)(k0 + ty + r*8) * N + n0 + tx];
  __syncthreads();
  #pragma unroll
  for (int r = 0; r < 4; ++r)
    wt[(size_t)(n0 + ty + r*8) * K + k0 + tx] = f2bf(t[tx][ty + r*8]);
}

// ---------------- bf16 MFMA GEMM: 128x128 tile, BK=32, 4 waves ----------------
// A: [M][K] bf16 row-major.  Bt: [N][K] bf16 (B transposed).  EPI 0: qkv scatter, 1: f32 out.
template<int EPI>
__global__ __launch_bounds__(256) void k_gemm(const u16* __restrict__ A,
                                              const u16* __restrict__ Bt,
                                              const float* __restrict__ bias,
                                              void* __restrict__ outp,
                                              int K) {
  __shared__ __align__(16) u16 lA[128*32];
  __shared__ __align__(16) u16 lB[128*32];
  int tid = threadIdx.x;
  int wave = tid >> 6, lane = tid & 63;
  int wr = wave >> 1, wc = wave & 1;
  int lrow = lane & 15, lgrp = lane >> 4;
  int row0 = blockIdx.y * 128, col0 = blockIdx.x * 128;

  f32x4 zero = {0.f, 0.f, 0.f, 0.f};
  f32x4 acc[4][4];
  #pragma unroll
  for (int m = 0; m < 4; ++m)
    #pragma unroll
    for (int n = 0; n < 4; ++n) acc[m][n] = zero;

  for (int kt = 0; kt < K; kt += 32) {
    // stage A,B tiles (8KB each) via global_load_lds width=16
    #pragma unroll
    for (int p = 0; p < 2; ++p) {
      int c = (wave*2 + p)*64 + lane;   // 16B chunk index in tile (0..511)
      int r = c >> 2, kc = c & 3;       // tile row, 16B chunk within row
      gload16(A  + (size_t)(row0 + r)*K + kt + kc*8,
              (__attribute__((address_space(3))) char*)lA + (wave*2 + p)*1024);
      gload16(Bt + (size_t)(col0 + r)*K + kt + kc*8,
              (__attribute__((address_space(3))) char*)lB + (wave*2 + p)*1024);
    }
    __syncthreads();
    bf16x8 af[4], bfr[4];
    #pragma unroll
    for (int m = 0; m < 4; ++m)
      af[m] = *(const bf16x8*)(lA + (wr*64 + m*16 + lrow)*32 + lgrp*8);
    #pragma unroll
    for (int n = 0; n < 4; ++n)
      bfr[n] = *(const bf16x8*)(lB + (wc*64 + n*16 + lrow)*32 + lgrp*8);
    #pragma unroll
    for (int m = 0; m < 4; ++m)
      #pragma unroll
      for (int n = 0; n < 4; ++n)
        acc[m][n] = __builtin_amdgcn_mfma_f32_16x16x32_bf16(af[m], bfr[n], acc[m][n], 0, 0, 0);
    __syncthreads();
  }

  #pragma unroll
  for (int m = 0; m < 4; ++m) {
    #pragma unroll
    for (int n = 0; n < 4; ++n) {
      int gcol = col0 + wc*64 + n*16 + lrow;
      float bv = bias[gcol];
      #pragma unroll
      for (int r = 0; r < 4; ++r) {
        int grow = row0 + wr*64 + m*16 + lgrp*4 + r;
        float val = acc[m][n][r] + bv;
        if (EPI == 0) {
          // scatter into q/k/v [B,H,T,HD] bf16 (contiguous blocks of BHTD_)
          int which = gcol >> 10, c = gcol & 1023;
          int hh = c >> 6, d = c & 63;
          int bb = grow >> 11, tt = grow & 2047;
          ((u16*)outp)[(size_t)which*BHTD_ + (((size_t)(bb*H_ + hh)*T_ + tt)*HD_ + d)] = f2bf(val);
        } else {
          ((float*)outp)[(size_t)grow*C_ + gcol] = val;
        }
      }
    }
  }
}

// ---------------- causal flash attention: block = (qtile, b*h), 4 waves x 32 rows ----------------
__global__ __launch_bounds__(256) void k_attn(const u16* __restrict__ q,
                                              const u16* __restrict__ k,
                                              const u16* __restrict__ v,
                                              u16* __restrict__ y) {
  __shared__ __align__(16) u16 vt[64*72];    // V^T [d][kv], padded rows (+8)
  __shared__ __align__(16) u16 pl[128*72];   // P   [qrow][kv], padded rows (+8)
  int tid = threadIdx.x;
  int wave = tid >> 6, lane = tid & 63;
  int lrow = lane & 15, lgrp = lane >> 4;
  int qt = blockIdx.x, bh = blockIdx.y;
  int bidx = bh >> 4, hh = bh & 15;
  const u16* qb = q + (size_t)bh * T_ * HD_;
  const u16* kb = k + (size_t)bh * T_ * HD_;
  const u16* vb = v + (size_t)bh * T_ * HD_;
  int qr0 = qt*128 + wave*32;   // this wave's first Q row

  // Q fragments held in registers for the whole kernel
  bf16x8 qf[2][2];
  #pragma unroll
  for (int m = 0; m < 2; ++m)
    #pragma unroll
    for (int ks = 0; ks < 2; ++ks)
      qf[m][ks] = *(const bf16x8*)(qb + (size_t)(qr0 + m*16 + lrow)*HD_ + ks*32 + lgrp*8);

  f32x4 zero = {0.f, 0.f, 0.f, 0.f};
  f32x4 o[2][4];
  float mrun[2][4], lrun[2][4];
  #pragma unroll
  for (int m = 0; m < 2; ++m) {
    #pragma unroll
    for (int d = 0; d < 4; ++d) o[m][d] = zero;
    #pragma unroll
    for (int r = 0; r < 4; ++r) { mrun[m][r] = -1e30f; lrun[m][r] = 0.f; }
  }

  int nt = 2*qt + 2;   // kv tiles needed for causal coverage of this q-block
  for (int kt = 0; kt < nt; ++kt) {
    int kv0 = kt * 64;
    {   // cooperative V^T staging (reg-staged so padding is legal)
      int kvr = tid >> 2, dp = (tid & 3) * 16;
      const u16* src = vb + (size_t)(kv0 + kvr)*HD_ + dp;
      bf16x8 a0 = *(const bf16x8*)src;
      bf16x8 a1 = *(const bf16x8*)(src + 8);
      #pragma unroll
      for (int j = 0; j < 8; ++j) vt[(dp + j)*72 + kvr] = (u16)a0[j];
      #pragma unroll
      for (int j = 0; j < 8; ++j) vt[(dp + 8 + j)*72 + kvr] = (u16)a1[j];
    }
    __syncthreads();

    if (kv0 <= qr0 + 31) {   // wave-uniform: skip fully-masked tiles (no barrier inside)
      // --- QK^T (K fragments straight from global; L2-resident) ---
      f32x4 s[2][4];
      #pragma unroll
      for (int m = 0; m < 2; ++m)
        #pragma unroll
        for (int n = 0; n < 4; ++n) s[m][n] = zero;
      #pragma unroll
      for (int ks = 0; ks < 2; ++ks) {
        bf16x8 kf[4];
        #pragma unroll
        for (int n = 0; n < 4; ++n)
          kf[n] = *(const bf16x8*)(kb + (size_t)(kv0 + n*16 + lrow)*HD_ + ks*32 + lgrp*8);
        #pragma unroll
        for (int m = 0; m < 2; ++m)
          #pragma unroll
          for (int n = 0; n < 4; ++n)
            s[m][n] = __builtin_amdgcn_mfma_f32_16x16x32_bf16(qf[m][ks], kf[n], s[m][n], 0, 0, 0);
      }

      // --- online softmax (row = C/D row: lgrp*4+r; 16-lane butterfly over cols) ---
      #pragma unroll
      for (int m = 0; m < 2; ++m) {
        #pragma unroll
        for (int r = 0; r < 4; ++r) {
          int grow = qr0 + m*16 + lgrp*4 + r;
          float pv[4];
          float vmax = -3.0e38f;
          #pragma unroll
          for (int n = 0; n < 4; ++n) {
            float sv = s[m][n][r] * 0.125f;
            int col = kv0 + n*16 + lrow;
            sv = (col > grow) ? -3.0e38f : sv;
            pv[n] = sv;
            vmax = fmaxf(vmax, sv);
          }
          #pragma unroll
          for (int off = 1; off < 16; off <<= 1)
            vmax = fmaxf(vmax, __shfl_xor(vmax, off));
          float mold = mrun[m][r];
          float mnew = fmaxf(mold, vmax);
          float ex = __expf(mold - mnew);   // first tile: exp(-1e30-x) -> 0
          mrun[m][r] = mnew;
          float rsum = 0.f;
          #pragma unroll
          for (int n = 0; n < 4; ++n) { float p = __expf(pv[n] - mnew); pv[n] = p; rsum += p; }
          #pragma unroll
          for (int off = 1; off < 16; off <<= 1)
            rsum += __shfl_xor(rsum, off);
          lrun[m][r] = lrun[m][r]*ex + rsum;
          #pragma unroll
          for (int d = 0; d < 4; ++d) o[m][d][r] *= ex;
          #pragma unroll
          for (int n = 0; n < 4; ++n)
            pl[(wave*32 + m*16 + lgrp*4 + r)*72 + n*16 + lrow] = f2bf(pv[n]);
        }
      }

      // --- PV (A=P from own LDS slice, B=V^T from LDS) ---
      #pragma unroll
      for (int ks = 0; ks < 2; ++ks) {
        bf16x8 pa[2], vf[4];
        #pragma unroll
        for (int m = 0; m < 2; ++m)
          pa[m] = *(const bf16x8*)(pl + (wave*32 + m*16 + lrow)*72 + ks*32 + lgrp*8);
        #pragma unroll
        for (int d = 0; d < 4; ++d)
          vf[d] = *(const bf16x8*)(vt + (d*16 + lrow)*72 + ks*32 + lgrp*8);
        #pragma unroll
        for (int m = 0; m < 2; ++m)
          #pragma unroll
          for (int d = 0; d < 4; ++d)
            o[m][d] = __builtin_amdgcn_mfma_f32_16x16x32_bf16(pa[m], vf[d], o[m][d], 0, 0, 0);
      }
    }
    __syncthreads();   // protect vt before next tile's staging
  }

  // epilogue: y[B,T,C] bf16
  #pragma unroll
  for (int m = 0; m < 2; ++m) {
    #pragma unroll
    for (int r = 0; r < 4; ++r) {
      int trow = qr0 + m*16 + lgrp*4 + r;
      float inv = 1.0f / lrun[m][r];
      #pragma unroll
      for (int d = 0; d < 4; ++d)
        y[(size_t)(bidx*T_ + trow)*C_ + hh*64 + d*16 + lrow] = f2bf(o[m][d][r] * inv);
    }
  }
}

extern "C" void kernel_launch(void* const* d_in, const int* in_sizes, int n_in,
                              void* d_out, int out_size, void* d_ws, size_t ws_size,
                              hipStream_t stream) {
  const float* x      = (const float*)d_in[0];
  const float* w_attn = (const float*)d_in[1];
  const float* b_attn = (const float*)d_in[2];
  const float* w_proj = (const float*)d_in[3];
  const float* b_proj = (const float*)d_in[4];

  char* ws = (char*)d_ws;
  size_t off = 0;
  auto walloc = [&](size_t bytes) -> void* {
    void* p = ws + off;
    off += (bytes + 255) & ~(size_t)255;
    return p;
  };
  u16* xbf = (u16*)walloc((size_t)BT_ * C_ * 2);      // x as bf16; later reused as y
  u16* wat = (u16*)walloc((size_t)C3_ * C_ * 2);      // w_attn^T bf16 [3C][C]
  u16* wpt = (u16*)walloc((size_t)C_ * C_ * 2);       // w_proj^T bf16 [C][C]
  u16* qkv = (u16*)walloc(3 * BHTD_ * 2);             // q,k,v contiguous [B,H,T,HD]
  u16* qp = qkv;
  u16* kp = qkv + BHTD_;
  u16* vp = qkv + 2*BHTD_;
  u16* ybf = xbf;   // alias: x consumed by GEMM1 before attention writes y
  // total workspace: ~72 MB

  k_cvt_bf16<<<(BT_*C_)/1024, 256, 0, stream>>>(x, xbf);
  k_transpose_bf16<<<dim3(C3_/32, C_/32), 256, 0, stream>>>(w_attn, wat, C_, C3_);
  k_transpose_bf16<<<dim3(C_/32, C_/32), 256, 0, stream>>>(w_proj, wpt, C_, C_);
  k_gemm<0><<<dim3(C3_/128, BT_/128), 256, 0, stream>>>(xbf, wat, b_attn, (void*)qkv, C_);
  k_attn<<<dim3(T_/128, B_*H_), 256, 0, stream>>>(qp, kp, vp, ybf);
  k_gemm<1><<<dim3(C_/128, BT_/128), 256, 0, stream>>>(ybf, wpt, b_proj, d_out, C_);
}

// Round 2
// 396.887 us; speedup vs baseline: 1.0991x; 1.0991x over previous
//
#include <hip/hip_runtime.h>

#define B_ 4
#define T_ 2048
#define C_ 1024
#define H_ 16
#define HD_ 64
#define BT_ (B_*T_)            // 8192
#define C3_ (3*C_)             // 3072
#define BHTD_ ((size_t)B_*H_*T_*HD_)  // 8388608 elements per q/k/v

using u16 = unsigned short;
using u32 = unsigned int;
using bf16x8 = __attribute__((ext_vector_type(8))) short;
using f32x4  = __attribute__((ext_vector_type(4))) float;
using u16x4  = __attribute__((ext_vector_type(4))) u16;

__device__ __forceinline__ u16 f2bf(float f) {
  u32 u = __float_as_uint(f);
  u += 0x7fffu + ((u >> 16) & 1u);   // round-to-nearest-even
  return (u16)(u >> 16);
}

__device__ __forceinline__ void gload16(const void* g,
                                        __attribute__((address_space(3))) void* l) {
  __builtin_amdgcn_global_load_lds((const __attribute__((address_space(1))) void*)g,
                                   l, 16, 0, 0);
}

// ---------------- convert fp32 -> bf16 (vectorized) ----------------
__global__ __launch_bounds__(256) void k_cvt_bf16(const float* __restrict__ in,
                                                  u16* __restrict__ out) {
  size_t i = (size_t)(blockIdx.x * blockDim.x + threadIdx.x) * 4;
  f32x4 f = *(const f32x4*)(in + i);
  u16x4 o;
  o[0] = f2bf(f[0]); o[1] = f2bf(f[1]); o[2] = f2bf(f[2]); o[3] = f2bf(f[3]);
  *(u16x4*)(out + i) = o;
}

// ---------------- transpose+convert: w[K][N] f32 -> wt[N][K] bf16 ----------------
__global__ __launch_bounds__(256) void k_transpose_bf16(const float* __restrict__ w,
                                                        u16* __restrict__ wt,
                                                        int K, int N) {
  __shared__ float t[32][33];
  int n0 = blockIdx.x * 32, k0 = blockIdx.y * 32;
  int tx = threadIdx.x & 31;
  int ty = threadIdx.x >> 5;   // 0..7
  #pragma unroll
  for (int r = 0; r < 4; ++r)
    t[ty + r*8][tx] = w[(size_t)(k0 + ty + r*8) * N + n0 + tx];
  __syncthreads();
  #pragma unroll
  for (int r = 0; r < 4; ++r)
    wt[(size_t)(n0 + ty + r*8) * K + k0 + tx] = f2bf(t[tx][ty + r*8]);
}

// ---------------- bf16 MFMA GEMM: 128x128 tile, BK=32, 4 waves ----------------
// A: [M][K] bf16 row-major.  Bt: [N][K] bf16 (B transposed).  EPI 0: qkv scatter, 1: f32 out.
// EPI 0 writes q,k as [B,H,T,HD] and v TRANSPOSED as [B,H,HD,T] so attention's
// PV B-fragments are contiguous global reads (no LDS transpose staging needed).
template<int EPI>
__global__ __launch_bounds__(256) void k_gemm(const u16* __restrict__ A,
                                              const u16* __restrict__ Bt,
                                              const float* __restrict__ bias,
                                              void* __restrict__ outp,
                                              int K) {
  __shared__ __align__(16) u16 lA[128*32];
  __shared__ __align__(16) u16 lB[128*32];
  int tid = threadIdx.x;
  int wave = tid >> 6, lane = tid & 63;
  int wr = wave >> 1, wc = wave & 1;
  int lrow = lane & 15, lgrp = lane >> 4;
  int row0 = blockIdx.y * 128, col0 = blockIdx.x * 128;

  f32x4 zero = {0.f, 0.f, 0.f, 0.f};
  f32x4 acc[4][4];
  #pragma unroll
  for (int m = 0; m < 4; ++m)
    #pragma unroll
    for (int n = 0; n < 4; ++n) acc[m][n] = zero;

  for (int kt = 0; kt < K; kt += 32) {
    // stage A,B tiles (8KB each) via global_load_lds width=16
    #pragma unroll
    for (int p = 0; p < 2; ++p) {
      int c = (wave*2 + p)*64 + lane;   // 16B chunk index in tile (0..511)
      int r = c >> 2, kc = c & 3;       // tile row, 16B chunk within row
      gload16(A  + (size_t)(row0 + r)*K + kt + kc*8,
              (__attribute__((address_space(3))) char*)lA + (wave*2 + p)*1024);
      gload16(Bt + (size_t)(col0 + r)*K + kt + kc*8,
              (__attribute__((address_space(3))) char*)lB + (wave*2 + p)*1024);
    }
    __syncthreads();
    bf16x8 af[4], bfr[4];
    #pragma unroll
    for (int m = 0; m < 4; ++m)
      af[m] = *(const bf16x8*)(lA + (wr*64 + m*16 + lrow)*32 + lgrp*8);
    #pragma unroll
    for (int n = 0; n < 4; ++n)
      bfr[n] = *(const bf16x8*)(lB + (wc*64 + n*16 + lrow)*32 + lgrp*8);
    #pragma unroll
    for (int m = 0; m < 4; ++m)
      #pragma unroll
      for (int n = 0; n < 4; ++n)
        acc[m][n] = __builtin_amdgcn_mfma_f32_16x16x32_bf16(af[m], bfr[n], acc[m][n], 0, 0, 0);
    __syncthreads();
  }

  #pragma unroll
  for (int m = 0; m < 4; ++m) {
    #pragma unroll
    for (int n = 0; n < 4; ++n) {
      int gcol = col0 + wc*64 + n*16 + lrow;
      float bv = bias[gcol];
      #pragma unroll
      for (int r = 0; r < 4; ++r) {
        int grow = row0 + wr*64 + m*16 + lgrp*4 + r;
        float val = acc[m][n][r] + bv;
        if (EPI == 0) {
          int which = gcol >> 10, c = gcol & 1023;
          int hh = c >> 6, d = c & 63;
          int bb = grow >> 11, tt = grow & 2047;
          size_t idx;
          if (which == 2)   // V transposed: [B,H,HD,T]
            idx = 2*BHTD_ + ((size_t)(bb*H_ + hh)*HD_ + d)*T_ + tt;
          else              // Q,K: [B,H,T,HD]
            idx = (size_t)which*BHTD_ + ((size_t)(bb*H_ + hh)*T_ + tt)*HD_ + d;
          ((u16*)outp)[idx] = f2bf(val);
        } else {
          ((float*)outp)[(size_t)grow*C_ + gcol] = val;
        }
      }
    }
  }
}

// ---------------- causal flash attention, barrier-free ----------------
// grid (16, B*H). Block = 4 waves. Waves 0,1 -> 64-row q-tile bx (+0/+32);
// waves 2,3 -> q-tile 31-bx. Every block does exactly 68 wave-tiles (balanced).
// K read from global [B,H,T,HD]; V read from global transposed [B,H,HD,T];
// only per-wave-private P round-trip uses LDS -> NO barriers in the loop.
__global__ __launch_bounds__(256, 4) void k_attn(const u16* __restrict__ q,
                                                 const u16* __restrict__ k,
                                                 const u16* __restrict__ vt,
                                                 u16* __restrict__ y) {
  __shared__ __align__(16) u16 pl[128*72];   // P [qrow][kv], stride 72 (per-wave slices)
  int tid = threadIdx.x;
  int wave = tid >> 6, lane = tid & 63;
  int lrow = lane & 15, lgrp = lane >> 4;
  int bx = blockIdx.x, bh = blockIdx.y;
  int bidx = bh >> 4, hh = bh & 15;
  const u16* qb = q  + (size_t)bh * T_ * HD_;
  const u16* kb = k  + (size_t)bh * T_ * HD_;
  const u16* vb = vt + (size_t)bh * HD_ * T_;   // [HD][T]
  int qtile = (wave < 2) ? bx : (31 - bx);      // 64-row tile index, 0..31
  int qr0 = qtile*64 + (wave & 1)*32;           // this wave's first Q row

  // Q fragments held in registers for the whole kernel
  bf16x8 qf[2][2];
  #pragma unroll
  for (int m = 0; m < 2; ++m)
    #pragma unroll
    for (int ks = 0; ks < 2; ++ks)
      qf[m][ks] = *(const bf16x8*)(qb + (size_t)(qr0 + m*16 + lrow)*HD_ + ks*32 + lgrp*8);

  f32x4 zero = {0.f, 0.f, 0.f, 0.f};
  f32x4 o[2][4];
  float mrun[2][4], lrun[2][4];
  #pragma unroll
  for (int m = 0; m < 2; ++m) {
    #pragma unroll
    for (int d = 0; d < 4; ++d) o[m][d] = zero;
    #pragma unroll
    for (int r = 0; r < 4; ++r) { mrun[m][r] = -1e30f; lrun[m][r] = 0.f; }
  }

  int nt = (qr0 >> 6) + 1;   // causal coverage: kv0 <= qr0+31
  for (int kt = 0; kt < nt; ++kt) {
    int kv0 = kt * 64;

    // --- QK^T (K fragments straight from global; L2-resident) ---
    f32x4 s[2][4];
    #pragma unroll
    for (int m = 0; m < 2; ++m)
      #pragma unroll
      for (int n = 0; n < 4; ++n) s[m][n] = zero;
    #pragma unroll
    for (int ks = 0; ks < 2; ++ks) {
      bf16x8 kf[4];
      #pragma unroll
      for (int n = 0; n < 4; ++n)
        kf[n] = *(const bf16x8*)(kb + (size_t)(kv0 + n*16 + lrow)*HD_ + ks*32 + lgrp*8);
      #pragma unroll
      for (int m = 0; m < 2; ++m)
        #pragma unroll
        for (int n = 0; n < 4; ++n)
          s[m][n] = __builtin_amdgcn_mfma_f32_16x16x32_bf16(qf[m][ks], kf[n], s[m][n], 0, 0, 0);
    }

    // --- online softmax (row = lgrp*4+r; 16-lane butterfly over cols) ---
    #pragma unroll
    for (int m = 0; m < 2; ++m) {
      #pragma unroll
      for (int r = 0; r < 4; ++r) {
        int grow = qr0 + m*16 + lgrp*4 + r;
        float pv[4];
        float vmax = -3.0e38f;
        #pragma unroll
        for (int n = 0; n < 4; ++n) {
          float sv = s[m][n][r] * 0.125f;
          int col = kv0 + n*16 + lrow;
          sv = (col > grow) ? -3.0e38f : sv;
          pv[n] = sv;
          vmax = fmaxf(vmax, sv);
        }
        #pragma unroll
        for (int off = 1; off < 16; off <<= 1)
          vmax = fmaxf(vmax, __shfl_xor(vmax, off));
        float mold = mrun[m][r];
        float mnew = fmaxf(mold, vmax);
        float ex = __expf(mold - mnew);   // first tile: exp(-1e30-x) -> 0
        mrun[m][r] = mnew;
        float rsum = 0.f;
        #pragma unroll
        for (int n = 0; n < 4; ++n) { float p = __expf(pv[n] - mnew); pv[n] = p; rsum += p; }
        #pragma unroll
        for (int off = 1; off < 16; off <<= 1)
          rsum += __shfl_xor(rsum, off);
        lrun[m][r] = lrun[m][r]*ex + rsum;
        #pragma unroll
        for (int d = 0; d < 4; ++d) o[m][d][r] *= ex;
        #pragma unroll
        for (int n = 0; n < 4; ++n)
          pl[(wave*32 + m*16 + lgrp*4 + r)*72 + n*16 + lrow] = f2bf(pv[n]);
      }
    }

    // --- PV: A = P from own LDS slice, B = V^T rows from global ---
    #pragma unroll
    for (int ks = 0; ks < 2; ++ks) {
      bf16x8 pa[2], vf[4];
      #pragma unroll
      for (int m = 0; m < 2; ++m)
        pa[m] = *(const bf16x8*)(pl + (wave*32 + m*16 + lrow)*72 + ks*32 + lgrp*8);
      #pragma unroll
      for (int d = 0; d < 4; ++d)
        vf[d] = *(const bf16x8*)(vb + (size_t)(d*16 + lrow)*T_ + kv0 + ks*32 + lgrp*8);
      #pragma unroll
      for (int m = 0; m < 2; ++m)
        #pragma unroll
        for (int d = 0; d < 4; ++d)
          o[m][d] = __builtin_amdgcn_mfma_f32_16x16x32_bf16(pa[m], vf[d], o[m][d], 0, 0, 0);
    }
  }

  // epilogue: y[B,T,C] bf16
  #pragma unroll
  for (int m = 0; m < 2; ++m) {
    #pragma unroll
    for (int r = 0; r < 4; ++r) {
      int trow = qr0 + m*16 + lgrp*4 + r;
      float inv = 1.0f / lrun[m][r];
      #pragma unroll
      for (int d = 0; d < 4; ++d)
        y[(size_t)(bidx*T_ + trow)*C_ + hh*64 + d*16 + lrow] = f2bf(o[m][d][r] * inv);
    }
  }
}

extern "C" void kernel_launch(void* const* d_in, const int* in_sizes, int n_in,
                              void* d_out, int out_size, void* d_ws, size_t ws_size,
                              hipStream_t stream) {
  const float* x      = (const float*)d_in[0];
  const float* w_attn = (const float*)d_in[1];
  const float* b_attn = (const float*)d_in[2];
  const float* w_proj = (const float*)d_in[3];
  const float* b_proj = (const float*)d_in[4];

  char* ws = (char*)d_ws;
  size_t off = 0;
  auto walloc = [&](size_t bytes) -> void* {
    void* p = ws + off;
    off += (bytes + 255) & ~(size_t)255;
    return p;
  };
  u16* xbf = (u16*)walloc((size_t)BT_ * C_ * 2);      // x as bf16; later reused as y
  u16* wat = (u16*)walloc((size_t)C3_ * C_ * 2);      // w_attn^T bf16 [3C][C]
  u16* wpt = (u16*)walloc((size_t)C_ * C_ * 2);       // w_proj^T bf16 [C][C]
  u16* qkv = (u16*)walloc(3 * BHTD_ * 2);             // q,k [B,H,T,HD]; v [B,H,HD,T]
  u16* qp = qkv;
  u16* kp = qkv + BHTD_;
  u16* vp = qkv + 2*BHTD_;
  u16* ybf = xbf;   // alias: x consumed by GEMM1 before attention writes y

  k_cvt_bf16<<<(BT_*C_)/1024, 256, 0, stream>>>(x, xbf);
  k_transpose_bf16<<<dim3(C3_/32, C_/32), 256, 0, stream>>>(w_attn, wat, C_, C3_);
  k_transpose_bf16<<<dim3(C_/32, C_/32), 256, 0, stream>>>(w_proj, wpt, C_, C_);
  k_gemm<0><<<dim3(C3_/128, BT_/128), 256, 0, stream>>>(xbf, wat, b_attn, (void*)qkv, C_);
  k_attn<<<dim3(16, B_*H_), 256, 0, stream>>>(qp, kp, vp, ybf);
  k_gemm<1><<<dim3(C_/128, BT_/128), 256, 0, stream>>>(ybf, wpt, b_proj, d_out, C_);
}

// Round 3
// 385.488 us; speedup vs baseline: 1.1316x; 1.0296x over previous
//
#include <hip/hip_runtime.h>

#define B_ 4
#define T_ 2048
#define C_ 1024
#define H_ 16
#define HD_ 64
#define BT_ (B_*T_)            // 8192
#define C3_ (3*C_)             // 3072
#define BHTD_ ((size_t)B_*H_*T_*HD_)  // 8388608 elements per q/k/v

using u16 = unsigned short;
using u32 = unsigned int;
using bf16x8 = __attribute__((ext_vector_type(8))) short;
using f32x4  = __attribute__((ext_vector_type(4))) float;
using u16x4  = __attribute__((ext_vector_type(4))) u16;

__device__ __forceinline__ u16 f2bf(float f) {
  u32 u = __float_as_uint(f);
  u += 0x7fffu + ((u >> 16) & 1u);   // round-to-nearest-even
  return (u16)(u >> 16);
}

__device__ __forceinline__ void gload16(const void* g,
                                        __attribute__((address_space(3))) void* l) {
  __builtin_amdgcn_global_load_lds((const __attribute__((address_space(1))) void*)g,
                                   l, 16, 0, 0);
}

// ---------------- convert fp32 -> bf16 (vectorized) ----------------
__global__ __launch_bounds__(256) void k_cvt_bf16(const float* __restrict__ in,
                                                  u16* __restrict__ out) {
  size_t i = (size_t)(blockIdx.x * blockDim.x + threadIdx.x) * 4;
  f32x4 f = *(const f32x4*)(in + i);
  u16x4 o;
  o[0] = f2bf(f[0]); o[1] = f2bf(f[1]); o[2] = f2bf(f[2]); o[3] = f2bf(f[3]);
  *(u16x4*)(out + i) = o;
}

// ---------------- transpose+convert: w[K][N] f32 -> wt[N][K] bf16 ----------------
__global__ __launch_bounds__(256) void k_transpose_bf16(const float* __restrict__ w,
                                                        u16* __restrict__ wt,
                                                        int K, int N) {
  __shared__ float t[32][33];
  int n0 = blockIdx.x * 32, k0 = blockIdx.y * 32;
  int tx = threadIdx.x & 31;
  int ty = threadIdx.x >> 5;   // 0..7
  #pragma unroll
  for (int r = 0; r < 4; ++r)
    t[ty + r*8][tx] = w[(size_t)(k0 + ty + r*8) * N + n0 + tx];
  __syncthreads();
  #pragma unroll
  for (int r = 0; r < 4; ++r)
    wt[(size_t)(n0 + ty + r*8) * K + k0 + tx] = f2bf(t[tx][ty + r*8]);
}

// ---------------- bf16 MFMA GEMM: 128x128 tile, BK=32, 4 waves ----------------
// A: [M][K] bf16 row-major.  Bt: [N][K] bf16 (B transposed).  EPI 0: qkv scatter, 1: f32 out.
// EPI 0: q scaled by 1/8 (softmax scale folded in); q,k as [B,H,T,HD]; v transposed [B,H,HD,T].
template<int EPI>
__global__ __launch_bounds__(256) void k_gemm(const u16* __restrict__ A,
                                              const u16* __restrict__ Bt,
                                              const float* __restrict__ bias,
                                              void* __restrict__ outp,
                                              int K) {
  __shared__ __align__(16) u16 lA[128*32];
  __shared__ __align__(16) u16 lB[128*32];
  int tid = threadIdx.x;
  int wave = tid >> 6, lane = tid & 63;
  int wr = wave >> 1, wc = wave & 1;
  int lrow = lane & 15, lgrp = lane >> 4;
  int row0 = blockIdx.y * 128, col0 = blockIdx.x * 128;

  f32x4 zero = {0.f, 0.f, 0.f, 0.f};
  f32x4 acc[4][4];
  #pragma unroll
  for (int m = 0; m < 4; ++m)
    #pragma unroll
    for (int n = 0; n < 4; ++n) acc[m][n] = zero;

  for (int kt = 0; kt < K; kt += 32) {
    #pragma unroll
    for (int p = 0; p < 2; ++p) {
      int c = (wave*2 + p)*64 + lane;   // 16B chunk index in tile (0..511)
      int r = c >> 2, kc = c & 3;       // tile row, 16B chunk within row
      gload16(A  + (size_t)(row0 + r)*K + kt + kc*8,
              (__attribute__((address_space(3))) char*)lA + (wave*2 + p)*1024);
      gload16(Bt + (size_t)(col0 + r)*K + kt + kc*8,
              (__attribute__((address_space(3))) char*)lB + (wave*2 + p)*1024);
    }
    __syncthreads();
    bf16x8 af[4], bfr[4];
    #pragma unroll
    for (int m = 0; m < 4; ++m)
      af[m] = *(const bf16x8*)(lA + (wr*64 + m*16 + lrow)*32 + lgrp*8);
    #pragma unroll
    for (int n = 0; n < 4; ++n)
      bfr[n] = *(const bf16x8*)(lB + (wc*64 + n*16 + lrow)*32 + lgrp*8);
    #pragma unroll
    for (int m = 0; m < 4; ++m)
      #pragma unroll
      for (int n = 0; n < 4; ++n)
        acc[m][n] = __builtin_amdgcn_mfma_f32_16x16x32_bf16(af[m], bfr[n], acc[m][n], 0, 0, 0);
    __syncthreads();
  }

  #pragma unroll
  for (int m = 0; m < 4; ++m) {
    #pragma unroll
    for (int n = 0; n < 4; ++n) {
      int gcol = col0 + wc*64 + n*16 + lrow;
      float bv = bias[gcol];
      #pragma unroll
      for (int r = 0; r < 4; ++r) {
        int grow = row0 + wr*64 + m*16 + lgrp*4 + r;
        float val = acc[m][n][r] + bv;
        if (EPI == 0) {
          int which = gcol >> 10, c = gcol & 1023;
          int hh = c >> 6, d = c & 63;
          int bb = grow >> 11, tt = grow & 2047;
          if (which == 0) val *= 0.125f;   // fold softmax 1/sqrt(HD) into q
          size_t idx;
          if (which == 2)   // V transposed: [B,H,HD,T]
            idx = 2*BHTD_ + ((size_t)(bb*H_ + hh)*HD_ + d)*T_ + tt;
          else              // Q,K: [B,H,T,HD]
            idx = (size_t)which*BHTD_ + ((size_t)(bb*H_ + hh)*T_ + tt)*HD_ + d;
          ((u16*)outp)[idx] = f2bf(val);
        } else {
          ((float*)outp)[(size_t)grow*C_ + gcol] = val;
        }
      }
    }
  }
}

// ---------------- causal flash attention, barrier-free, wave-balanced ----------------
// 1024 blocks x 4 waves. Each wave owns TWO 16-row q-strips (p, 127-p): exactly 33
// KV-tile iterations per wave -> zero imbalance. Block->head mapping groups 8 heads
// per XCD so each XCD's L2 holds its heads' K/V (8 x 512KB = 4MB).
// K from global [B,H,T,HD]; V from global transposed [B,H,HD,T]; only per-wave-private
// P round-trip uses LDS -> no barriers anywhere.
__global__ __launch_bounds__(256, 4) void k_attn(const u16* __restrict__ q,
                                                 const u16* __restrict__ k,
                                                 const u16* __restrict__ vt,
                                                 u16* __restrict__ y) {
  __shared__ __align__(16) u16 pl[64*72];   // P [4 waves x 16 rows][kv], stride 72
  int tid = threadIdx.x;
  int wave = tid >> 6, lane = tid & 63;
  int lrow = lane & 15, lgrp = lane >> 4;
  int L = blockIdx.x;
  int xcd = L & 7, idx = L >> 3;         // consecutive ids round-robin XCDs
  int bh = xcd*8 + (idx >> 4);           // 8 heads per XCD -> K/V L2-resident
  int xb = idx & 15;
  int bidx = bh >> 4, hh = bh & 15;
  const u16* qb = q  + (size_t)bh * T_ * HD_;
  const u16* kb = k  + (size_t)bh * T_ * HD_;
  const u16* vb = vt + (size_t)bh * HD_ * T_;   // [HD][T]
  u16* pls = pl + wave*16*72;            // per-wave-private slice

  f32x4 zero = {0.f, 0.f, 0.f, 0.f};

  auto strip = [&](int s) {
    int qr0 = s * 16;
    bf16x8 qf[2];
    #pragma unroll
    for (int ks = 0; ks < 2; ++ks)
      qf[ks] = *(const bf16x8*)(qb + (size_t)(qr0 + lrow)*HD_ + ks*32 + lgrp*8);

    f32x4 o[4];
    float mrun[4], lrun[4];
    #pragma unroll
    for (int d = 0; d < 4; ++d) o[d] = zero;
    #pragma unroll
    for (int r = 0; r < 4; ++r) { mrun[r] = -1e30f; lrun[r] = 0.f; }

    auto tile = [&](int kv0, bool domask) {
      // --- QK^T ---
      f32x4 sacc[4];
      #pragma unroll
      for (int n = 0; n < 4; ++n) sacc[n] = zero;
      #pragma unroll
      for (int ks = 0; ks < 2; ++ks) {
        bf16x8 kf[4];
        #pragma unroll
        for (int n = 0; n < 4; ++n)
          kf[n] = *(const bf16x8*)(kb + (size_t)(kv0 + n*16 + lrow)*HD_ + ks*32 + lgrp*8);
        #pragma unroll
        for (int n = 0; n < 4; ++n)
          sacc[n] = __builtin_amdgcn_mfma_f32_16x16x32_bf16(qf[ks], kf[n], sacc[n], 0, 0, 0);
      }

      // --- V loads issued early; latency hidden under softmax ---
      bf16x8 vf[2][4];
      #pragma unroll
      for (int ks = 0; ks < 2; ++ks)
        #pragma unroll
        for (int d = 0; d < 4; ++d)
          vf[ks][d] = *(const bf16x8*)(vb + (size_t)(d*16 + lrow)*T_ + kv0 + ks*32 + lgrp*8);

      // --- online softmax (4 rows: lgrp*4+r; 16-lane butterflies) ---
      #pragma unroll
      for (int r = 0; r < 4; ++r) {
        int grow = qr0 + lgrp*4 + r;
        float pv[4];
        #pragma unroll
        for (int n = 0; n < 4; ++n) {
          float sv = sacc[n][r];
          if (domask) {
            int col = kv0 + n*16 + lrow;
            sv = (col > grow) ? -3.0e38f : sv;
          }
          pv[n] = sv;
        }
        float vmax = fmaxf(fmaxf(pv[0], pv[1]), fmaxf(pv[2], pv[3]));
        #pragma unroll
        for (int off = 1; off < 16; off <<= 1)
          vmax = fmaxf(vmax, __shfl_xor(vmax, off));
        float mold = mrun[r];
        float mnew = fmaxf(mold, vmax);
        float ex = __expf(mold - mnew);
        mrun[r] = mnew;
        float rsum = 0.f;
        #pragma unroll
        for (int n = 0; n < 4; ++n) { float p = __expf(pv[n] - mnew); pv[n] = p; rsum += p; }
        #pragma unroll
        for (int off = 1; off < 16; off <<= 1)
          rsum += __shfl_xor(rsum, off);
        lrun[r] = lrun[r]*ex + rsum;
        #pragma unroll
        for (int d = 0; d < 4; ++d) o[d][r] *= ex;
        #pragma unroll
        for (int n = 0; n < 4; ++n)
          pl[(wave*16 + lgrp*4 + r)*72 + n*16 + lrow] = f2bf(pv[n]);
      }

      // --- PV ---
      #pragma unroll
      for (int ks = 0; ks < 2; ++ks) {
        bf16x8 pa = *(const bf16x8*)(pls + lrow*72 + ks*32 + lgrp*8);
        #pragma unroll
        for (int d = 0; d < 4; ++d)
          o[d] = __builtin_amdgcn_mfma_f32_16x16x32_bf16(pa, vf[ks][d], o[d], 0, 0, 0);
      }
    };

    int nt = (s >> 2) + 1;
    for (int kt = 0; kt < nt - 1; ++kt) tile(kt*64, false);
    tile((nt - 1)*64, true);

    // epilogue: y[B,T,C] bf16
    #pragma unroll
    for (int r = 0; r < 4; ++r) {
      int trow = qr0 + lgrp*4 + r;
      float inv = 1.0f / lrun[r];
      #pragma unroll
      for (int d = 0; d < 4; ++d)
        y[(size_t)(bidx*T_ + trow)*C_ + hh*64 + d*16 + lrow] = f2bf(o[d][r] * inv);
    }
  };

  int p = xb*4 + wave;   // 0..63
  strip(p);
  strip(127 - p);
}

extern "C" void kernel_launch(void* const* d_in, const int* in_sizes, int n_in,
                              void* d_out, int out_size, void* d_ws, size_t ws_size,
                              hipStream_t stream) {
  const float* x      = (const float*)d_in[0];
  const float* w_attn = (const float*)d_in[1];
  const float* b_attn = (const float*)d_in[2];
  const float* w_proj = (const float*)d_in[3];
  const float* b_proj = (const float*)d_in[4];

  char* ws = (char*)d_ws;
  size_t off = 0;
  auto walloc = [&](size_t bytes) -> void* {
    void* p = ws + off;
    off += (bytes + 255) & ~(size_t)255;
    return p;
  };
  u16* xbf = (u16*)walloc((size_t)BT_ * C_ * 2);      // x as bf16; later reused as y
  u16* wat = (u16*)walloc((size_t)C3_ * C_ * 2);      // w_attn^T bf16 [3C][C]
  u16* wpt = (u16*)walloc((size_t)C_ * C_ * 2);       // w_proj^T bf16 [C][C]
  u16* qkv = (u16*)walloc(3 * BHTD_ * 2);             // q,k [B,H,T,HD]; v [B,H,HD,T]
  u16* qp = qkv;
  u16* kp = qkv + BHTD_;
  u16* vp = qkv + 2*BHTD_;
  u16* ybf = xbf;   // alias: x consumed by GEMM1 before attention writes y

  k_cvt_bf16<<<(BT_*C_)/1024, 256, 0, stream>>>(x, xbf);
  k_transpose_bf16<<<dim3(C3_/32, C_/32), 256, 0, stream>>>(w_attn, wat, C_, C3_);
  k_transpose_bf16<<<dim3(C_/32, C_/32), 256, 0, stream>>>(w_proj, wpt, C_, C_);
  k_gemm<0><<<dim3(C3_/128, BT_/128), 256, 0, stream>>>(xbf, wat, b_attn, (void*)qkv, C_);
  k_attn<<<dim3(1024), 256, 0, stream>>>(qp, kp, vp, ybf);
  k_gemm<1><<<dim3(C_/128, BT_/128), 256, 0, stream>>>(ybf, wpt, b_proj, d_out, C_);
}

// Round 4
// 263.403 us; speedup vs baseline: 1.6561x; 1.4635x over previous
//
#include <hip/hip_runtime.h>
#include <hip/hip_bf16.h>

#define B_ 4
#define T_ 2048
#define C_ 1024
#define H_ 16
#define HD_ 64
#define BT_ (B_*T_)            // 8192
#define C3_ (3*C_)             // 3072
#define BHTD_ ((size_t)B_*H_*T_*HD_)  // 8388608 elements per q/k/v

// softmax scale 1/8 with log2(e) folded in (attention uses exp2)
#define QSCALE 0.18033688011112042f

using u16 = unsigned short;
using u32 = unsigned int;
using bf16x8 = __attribute__((ext_vector_type(8))) short;
using f32x4  = __attribute__((ext_vector_type(4))) float;
using f32x16 = __attribute__((ext_vector_type(16))) float;
using u16x4  = __attribute__((ext_vector_type(4))) u16;
typedef int i32x2 __attribute__((ext_vector_type(2)));

#if __has_builtin(__builtin_amdgcn_exp2f)
#define EXP2(x) __builtin_amdgcn_exp2f(x)
#else
#define EXP2(x) exp2f(x)
#endif

__device__ __forceinline__ u16 f2bf(float f) {
  u32 u = __float_as_uint(f);
  u += 0x7fffu + ((u >> 16) & 1u);   // round-to-nearest-even
  return (u16)(u >> 16);
}

// pack two floats to (lo,hi) bf16 in one u32
__device__ __forceinline__ u32 pkbf(float lo, float hi) {
  __hip_bfloat162 t = __float22bfloat162_rn(make_float2(lo, hi));
  u32 r; __builtin_memcpy(&r, &t, 4); return r;
}

// exchange with the lane^32 partner: a' = (lo: own a, hi: partner a), b' = (lo: partner b-pos... )
__device__ __forceinline__ void plswap(u32 &a, u32 &b) {
#if __has_builtin(__builtin_amdgcn_permlane32_swap)
  i32x2 r = __builtin_amdgcn_permlane32_swap((int)a, (int)b, false, false);
  a = (u32)r[0]; b = (u32)r[1];
#else
  asm volatile("v_permlane32_swap_b32 %0, %1" : "+v"(a), "+v"(b));
#endif
}

__device__ __forceinline__ float xmaxf(float x) {
  u32 a = __float_as_uint(x), b = a;
  plswap(a, b);
  return fmaxf(__uint_as_float(a), __uint_as_float(b));
}
__device__ __forceinline__ float xaddf(float x) {
  u32 a = __float_as_uint(x), b = a;
  plswap(a, b);
  return __uint_as_float(a) + __uint_as_float(b);
}

__device__ __forceinline__ void gload16(const void* g,
                                        __attribute__((address_space(3))) void* l) {
  __builtin_amdgcn_global_load_lds((const __attribute__((address_space(1))) void*)g,
                                   l, 16, 0, 0);
}

// ---------------- convert fp32 -> bf16 (vectorized) ----------------
__global__ __launch_bounds__(256) void k_cvt_bf16(const float* __restrict__ in,
                                                  u16* __restrict__ out) {
  size_t i = (size_t)(blockIdx.x * blockDim.x + threadIdx.x) * 4;
  f32x4 f = *(const f32x4*)(in + i);
  u16x4 o;
  o[0] = f2bf(f[0]); o[1] = f2bf(f[1]); o[2] = f2bf(f[2]); o[3] = f2bf(f[3]);
  *(u16x4*)(out + i) = o;
}

// ---------------- transpose+convert: w[K][N] f32 -> wt[N][K] bf16 ----------------
__global__ __launch_bounds__(256) void k_transpose_bf16(const float* __restrict__ w,
                                                        u16* __restrict__ wt,
                                                        int K, int N) {
  __shared__ float t[32][33];
  int n0 = blockIdx.x * 32, k0 = blockIdx.y * 32;
  int tx = threadIdx.x & 31;
  int ty = threadIdx.x >> 5;   // 0..7
  #pragma unroll
  for (int r = 0; r < 4; ++r)
    t[ty + r*8][tx] = w[(size_t)(k0 + ty + r*8) * N + n0 + tx];
  __syncthreads();
  #pragma unroll
  for (int r = 0; r < 4; ++r)
    wt[(size_t)(n0 + ty + r*8) * K + k0 + tx] = f2bf(t[tx][ty + r*8]);
}

// ---------------- bf16 MFMA GEMM: 128x128 tile, BK=32, 4 waves ----------------
// A: [M][K] bf16 row-major.  Bt: [N][K] bf16 (B transposed).  EPI 0: qkv scatter, 1: f32 out.
// EPI 0: q scaled by QSCALE; q,k as [B,H,T,HD]; v transposed [B,H,HD,T].
template<int EPI>
__global__ __launch_bounds__(256) void k_gemm(const u16* __restrict__ A,
                                              const u16* __restrict__ Bt,
                                              const float* __restrict__ bias,
                                              void* __restrict__ outp,
                                              int K) {
  __shared__ __align__(16) u16 lA[128*32];
  __shared__ __align__(16) u16 lB[128*32];
  int tid = threadIdx.x;
  int wave = tid >> 6, lane = tid & 63;
  int wr = wave >> 1, wc = wave & 1;
  int lrow = lane & 15, lgrp = lane >> 4;
  int row0 = blockIdx.y * 128, col0 = blockIdx.x * 128;

  f32x4 zero = {0.f, 0.f, 0.f, 0.f};
  f32x4 acc[4][4];
  #pragma unroll
  for (int m = 0; m < 4; ++m)
    #pragma unroll
    for (int n = 0; n < 4; ++n) acc[m][n] = zero;

  for (int kt = 0; kt < K; kt += 32) {
    #pragma unroll
    for (int p = 0; p < 2; ++p) {
      int c = (wave*2 + p)*64 + lane;   // 16B chunk index in tile (0..511)
      int r = c >> 2, kc = c & 3;       // tile row, 16B chunk within row
      gload16(A  + (size_t)(row0 + r)*K + kt + kc*8,
              (__attribute__((address_space(3))) char*)lA + (wave*2 + p)*1024);
      gload16(Bt + (size_t)(col0 + r)*K + kt + kc*8,
              (__attribute__((address_space(3))) char*)lB + (wave*2 + p)*1024);
    }
    __syncthreads();
    bf16x8 af[4], bfr[4];
    #pragma unroll
    for (int m = 0; m < 4; ++m)
      af[m] = *(const bf16x8*)(lA + (wr*64 + m*16 + lrow)*32 + lgrp*8);
    #pragma unroll
    for (int n = 0; n < 4; ++n)
      bfr[n] = *(const bf16x8*)(lB + (wc*64 + n*16 + lrow)*32 + lgrp*8);
    #pragma unroll
    for (int m = 0; m < 4; ++m)
      #pragma unroll
      for (int n = 0; n < 4; ++n)
        acc[m][n] = __builtin_amdgcn_mfma_f32_16x16x32_bf16(af[m], bfr[n], acc[m][n], 0, 0, 0);
    __syncthreads();
  }

  #pragma unroll
  for (int m = 0; m < 4; ++m) {
    #pragma unroll
    for (int n = 0; n < 4; ++n) {
      int gcol = col0 + wc*64 + n*16 + lrow;
      float bv = bias[gcol];
      #pragma unroll
      for (int r = 0; r < 4; ++r) {
        int grow = row0 + wr*64 + m*16 + lgrp*4 + r;
        float val = acc[m][n][r] + bv;
        if (EPI == 0) {
          int which = gcol >> 10, c = gcol & 1023;
          int hh = c >> 6, d = c & 63;
          int bb = grow >> 11, tt = grow & 2047;
          if (which == 0) val *= QSCALE;   // fold softmax scale * log2(e) into q
          size_t idx;
          if (which == 2)   // V transposed: [B,H,HD,T]
            idx = 2*BHTD_ + ((size_t)(bb*H_ + hh)*HD_ + d)*T_ + tt;
          else              // Q,K: [B,H,T,HD]
            idx = (size_t)which*BHTD_ + ((size_t)(bb*H_ + hh)*T_ + tt)*HD_ + d;
          ((u16*)outp)[idx] = f2bf(val);
        } else {
          ((float*)outp)[(size_t)grow*C_ + gcol] = val;
        }
      }
    }
  }
}

// ---------------- causal flash attention: swapped-operand, fully in-register ----------------
// 512 blocks x 4 waves. head = bid&63 (8 heads per XCD -> K/V L2-resident).
// Wave owns strip pair (p, 63-p), 32 q-rows each: exactly 33 KV tiles per wave.
// QK^T = mfma32(K,Q) -> S^T with col = q = lane&31: softmax per-lane (in-lane tree +
// one permlane32_swap). PV = mfma32(V^T, P) -> O^T, col = q: rescale in-lane.
// ZERO LDS, zero barriers, zero ds-pipe ops.
__global__ __launch_bounds__(256, 2) void k_attn(const u16* __restrict__ q,
                                                 const u16* __restrict__ k,
                                                 const u16* __restrict__ vt,
                                                 u16* __restrict__ y) {
  int tid = threadIdx.x;
  int wave = tid >> 6, lane = tid & 63;
  int l31 = lane & 31, hi = lane >> 5;
  int bid = blockIdx.x;
  int head = bid & 63;                    // bid&7 = head&7 -> stable XCD per head
  int pidx = (bid >> 6) * 4 + wave;       // 0..31
  int bidx = head >> 4, hh = head & 15;
  const u16* qb = q  + (size_t)head * T_ * HD_;
  const u16* kb = k  + (size_t)head * T_ * HD_;
  const u16* vb = vt + (size_t)head * HD_ * T_;   // [HD][T]

  f32x16 zero16 = {0.f,0.f,0.f,0.f,0.f,0.f,0.f,0.f,0.f,0.f,0.f,0.f,0.f,0.f,0.f,0.f};

  auto strip = [&](int s) {
    int qr0 = s * 32;
    const u16* qrow = qb + (size_t)(qr0 + l31)*HD_ + hi*8;
    bf16x8 qf0 = *(const bf16x8*)(qrow);
    bf16x8 qf1 = *(const bf16x8*)(qrow + 16);
    bf16x8 qf2 = *(const bf16x8*)(qrow + 32);
    bf16x8 qf3 = *(const bf16x8*)(qrow + 48);

    f32x16 od0 = zero16, od1 = zero16;
    float mrun = -1e30f, lrun = 0.f;
    int qg = qr0 + l31;

    auto tile = [&](int kv0, bool domask) {
      // --- K fragments (global, L2-resident) ---
      const u16* krow = kb + (size_t)(kv0 + l31)*HD_ + hi*8;
      bf16x8 kf00 = *(const bf16x8*)(krow);
      bf16x8 kf01 = *(const bf16x8*)(krow + 16);
      bf16x8 kf02 = *(const bf16x8*)(krow + 32);
      bf16x8 kf03 = *(const bf16x8*)(krow + 48);
      const u16* krow1 = krow + 32*HD_;
      bf16x8 kf10 = *(const bf16x8*)(krow1);
      bf16x8 kf11 = *(const bf16x8*)(krow1 + 16);
      bf16x8 kf12 = *(const bf16x8*)(krow1 + 32);
      bf16x8 kf13 = *(const bf16x8*)(krow1 + 48);

      // --- QK^T swapped: S^T[k][q], col = q = lane&31 ---
      f32x16 s0 = zero16, s1 = zero16;
      s0 = __builtin_amdgcn_mfma_f32_32x32x16_bf16(kf00, qf0, s0, 0, 0, 0);
      s1 = __builtin_amdgcn_mfma_f32_32x32x16_bf16(kf10, qf0, s1, 0, 0, 0);
      s0 = __builtin_amdgcn_mfma_f32_32x32x16_bf16(kf01, qf1, s0, 0, 0, 0);
      s1 = __builtin_amdgcn_mfma_f32_32x32x16_bf16(kf11, qf1, s1, 0, 0, 0);
      s0 = __builtin_amdgcn_mfma_f32_32x32x16_bf16(kf02, qf2, s0, 0, 0, 0);
      s1 = __builtin_amdgcn_mfma_f32_32x32x16_bf16(kf12, qf2, s1, 0, 0, 0);
      s0 = __builtin_amdgcn_mfma_f32_32x32x16_bf16(kf03, qf3, s0, 0, 0, 0);
      s1 = __builtin_amdgcn_mfma_f32_32x32x16_bf16(kf13, qf3, s1, 0, 0, 0);

      // --- V^T fragments issued early; latency hidden under softmax ---
      const u16* vrow = vb + (size_t)l31*T_ + kv0 + hi*8;
      bf16x8 vf00 = *(const bf16x8*)(vrow);
      bf16x8 vf01 = *(const bf16x8*)(vrow + 16);
      bf16x8 vf02 = *(const bf16x8*)(vrow + 32);
      bf16x8 vf03 = *(const bf16x8*)(vrow + 48);
      const u16* vrow1 = vrow + 32*T_;
      bf16x8 vf10 = *(const bf16x8*)(vrow1);
      bf16x8 vf11 = *(const bf16x8*)(vrow1 + 16);
      bf16x8 vf12 = *(const bf16x8*)(vrow1 + 32);
      bf16x8 vf13 = *(const bf16x8*)(vrow1 + 48);

      // --- causal mask (last tile only); k_local = (reg&3)+8*(reg>>2)+4*hi ---
      if (domask) {
        #pragma unroll
        for (int r = 0; r < 16; ++r) {
          int kl = (r & 3) + 8*(r >> 2) + 4*hi;
          if (kv0 + kl      > qg) s0[r] = -1e30f;
          if (kv0 + 32 + kl > qg) s1[r] = -1e30f;
        }
      }

      // --- in-lane max tree + partner combine ---
      float t[16];
      #pragma unroll
      for (int i = 0; i < 16; ++i) t[i] = fmaxf(s0[i], s1[i]);
      #pragma unroll
      for (int off = 8; off > 0; off >>= 1)
        #pragma unroll
        for (int i = 0; i < 8; ++i)
          if (i < off) t[i] = fmaxf(t[i], t[i + off]);
      float pmax = xmaxf(t[0]);

      float mnew = fmaxf(mrun, pmax);
      float ex = EXP2(mrun - mnew);
      mrun = mnew;

      // --- exponentials (in-place) + sum ---
      #pragma unroll
      for (int i = 0; i < 16; ++i) s0[i] = EXP2(s0[i] - mnew);
      #pragma unroll
      for (int i = 0; i < 16; ++i) s1[i] = EXP2(s1[i] - mnew);
      float u[16];
      #pragma unroll
      for (int i = 0; i < 16; ++i) u[i] = s0[i] + s1[i];
      #pragma unroll
      for (int off = 8; off > 0; off >>= 1)
        #pragma unroll
        for (int i = 0; i < 8; ++i)
          if (i < off) u[i] = u[i] + u[i + off];
      float rsum = xaddf(u[0]);
      lrun = lrun * ex + rsum;

      // --- rescale O^T (in-lane: col = q) ---
      #pragma unroll
      for (int i = 0; i < 16; ++i) { od0[i] *= ex; od1[i] *= ex; }

      // --- build P fragments: cvt_pk pairs + permlane32_swap (T12) ---
      bf16x8 pf0, pf1, pf2, pf3;
      {
        u32 a0 = pkbf(s0[0], s0[1]),   a1 = pkbf(s0[2], s0[3]);
        u32 b0 = pkbf(s0[4], s0[5]),   b1 = pkbf(s0[6], s0[7]);
        plswap(a0, b0); plswap(a1, b1);
        u32 wa[4] = {a0, a1, b0, b1};
        __builtin_memcpy(&pf0, wa, 16);
      }
      {
        u32 a0 = pkbf(s0[8], s0[9]),   a1 = pkbf(s0[10], s0[11]);
        u32 b0 = pkbf(s0[12], s0[13]), b1 = pkbf(s0[14], s0[15]);
        plswap(a0, b0); plswap(a1, b1);
        u32 wa[4] = {a0, a1, b0, b1};
        __builtin_memcpy(&pf1, wa, 16);
      }
      {
        u32 a0 = pkbf(s1[0], s1[1]),   a1 = pkbf(s1[2], s1[3]);
        u32 b0 = pkbf(s1[4], s1[5]),   b1 = pkbf(s1[6], s1[7]);
        plswap(a0, b0); plswap(a1, b1);
        u32 wa[4] = {a0, a1, b0, b1};
        __builtin_memcpy(&pf2, wa, 16);
      }
      {
        u32 a0 = pkbf(s1[8], s1[9]),   a1 = pkbf(s1[10], s1[11]);
        u32 b0 = pkbf(s1[12], s1[13]), b1 = pkbf(s1[14], s1[15]);
        plswap(a0, b0); plswap(a1, b1);
        u32 wa[4] = {a0, a1, b0, b1};
        __builtin_memcpy(&pf3, wa, 16);
      }

      // --- PV swapped: O^T[d][q] += V^T-frag x P-frag ---
      od0 = __builtin_amdgcn_mfma_f32_32x32x16_bf16(vf00, pf0, od0, 0, 0, 0);
      od0 = __builtin_amdgcn_mfma_f32_32x32x16_bf16(vf01, pf1, od0, 0, 0, 0);
      od0 = __builtin_amdgcn_mfma_f32_32x32x16_bf16(vf02, pf2, od0, 0, 0, 0);
      od0 = __builtin_amdgcn_mfma_f32_32x32x16_bf16(vf03, pf3, od0, 0, 0, 0);
      od1 = __builtin_amdgcn_mfma_f32_32x32x16_bf16(vf10, pf0, od1, 0, 0, 0);
      od1 = __builtin_amdgcn_mfma_f32_32x32x16_bf16(vf11, pf1, od1, 0, 0, 0);
      od1 = __builtin_amdgcn_mfma_f32_32x32x16_bf16(vf12, pf2, od1, 0, 0, 0);
      od1 = __builtin_amdgcn_mfma_f32_32x32x16_bf16(vf13, pf3, od1, 0, 0, 0);
    };

    int nt = (s >> 1) + 1;
    for (int kt = 0; kt < nt - 1; ++kt) tile(kt*64, false);
    tile((nt - 1)*64, true);

    // --- epilogue: y[B,T,C] bf16; row = qr0+l31, d = d0*32 + (2r&3)+8*(r>>1)+4*hi ---
    float inv = 1.0f / lrun;
    u16* yrow = y + ((size_t)(bidx*T_) + qr0 + l31)*C_ + hh*64;
    #pragma unroll
    for (int r = 0; r < 8; ++r) {
      int dp = ((2*r) & 3) + 8*(r >> 1) + 4*hi;
      u32 w0 = pkbf(od0[2*r]*inv, od0[2*r+1]*inv);
      u32 w1 = pkbf(od1[2*r]*inv, od1[2*r+1]*inv);
      *(u32*)(yrow + dp)      = w0;
      *(u32*)(yrow + 32 + dp) = w1;
    }
  };

  strip(pidx);
  strip(63 - pidx);
}

extern "C" void kernel_launch(void* const* d_in, const int* in_sizes, int n_in,
                              void* d_out, int out_size, void* d_ws, size_t ws_size,
                              hipStream_t stream) {
  const float* x      = (const float*)d_in[0];
  const float* w_attn = (const float*)d_in[1];
  const float* b_attn = (const float*)d_in[2];
  const float* w_proj = (const float*)d_in[3];
  const float* b_proj = (const float*)d_in[4];

  char* ws = (char*)d_ws;
  size_t off = 0;
  auto walloc = [&](size_t bytes) -> void* {
    void* p = ws + off;
    off += (bytes + 255) & ~(size_t)255;
    return p;
  };
  u16* xbf = (u16*)walloc((size_t)BT_ * C_ * 2);      // x as bf16; later reused as y
  u16* wat = (u16*)walloc((size_t)C3_ * C_ * 2);      // w_attn^T bf16 [3C][C]
  u16* wpt = (u16*)walloc((size_t)C_ * C_ * 2);       // w_proj^T bf16 [C][C]
  u16* qkv = (u16*)walloc(3 * BHTD_ * 2);             // q,k [B,H,T,HD]; v [B,H,HD,T]
  u16* qp = qkv;
  u16* kp = qkv + BHTD_;
  u16* vp = qkv + 2*BHTD_;
  u16* ybf = xbf;   // alias: x consumed by GEMM1 before attention writes y

  k_cvt_bf16<<<(BT_*C_)/1024, 256, 0, stream>>>(x, xbf);
  k_transpose_bf16<<<dim3(C3_/32, C_/32), 256, 0, stream>>>(w_attn, wat, C_, C3_);
  k_transpose_bf16<<<dim3(C_/32, C_/32), 256, 0, stream>>>(w_proj, wpt, C_, C_);
  k_gemm<0><<<dim3(C3_/128, BT_/128), 256, 0, stream>>>(xbf, wat, b_attn, (void*)qkv, C_);
  k_attn<<<dim3(512), 256, 0, stream>>>(qp, kp, vp, ybf);
  k_gemm<1><<<dim3(C_/128, BT_/128), 256, 0, stream>>>(ybf, wpt, b_proj, d_out, C_);
}

// Round 5
// 261.485 us; speedup vs baseline: 1.6682x; 1.0073x over previous
//
#include <hip/hip_runtime.h>
#include <hip/hip_bf16.h>

#define B_ 4
#define T_ 2048
#define C_ 1024
#define H_ 16
#define HD_ 64
#define BT_ (B_*T_)            // 8192
#define C3_ (3*C_)             // 3072
#define BHTD_ ((size_t)B_*H_*T_*HD_)  // 8388608 elements per q/k/v

// softmax scale 1/8 with log2(e) folded in (attention uses exp2)
#define QSCALE 0.18033688011112042f

using u16 = unsigned short;
using u32 = unsigned int;
using bf16x8 = __attribute__((ext_vector_type(8))) short;
using f32x4  = __attribute__((ext_vector_type(4))) float;
using f32x16 = __attribute__((ext_vector_type(16))) float;
using u16x4  = __attribute__((ext_vector_type(4))) u16;
typedef int i32x2 __attribute__((ext_vector_type(2)));

#if __has_builtin(__builtin_amdgcn_exp2f)
#define EXP2(x) __builtin_amdgcn_exp2f(x)
#else
#define EXP2(x) exp2f(x)
#endif

__device__ __forceinline__ u16 f2bf(float f) {
  u32 u = __float_as_uint(f);
  u += 0x7fffu + ((u >> 16) & 1u);   // round-to-nearest-even
  return (u16)(u >> 16);
}

// v_cvt_pk_bf16_f32: one instruction packs two f32 -> two bf16 (RTNE)
__device__ __forceinline__ u32 cvtpk(float lo, float hi) {
  u32 r;
  asm("v_cvt_pk_bf16_f32 %0, %1, %2" : "=v"(r) : "v"(lo), "v"(hi));
  return r;
}

// exchange with the lane^32 partner
__device__ __forceinline__ void plswap(u32 &a, u32 &b) {
#if __has_builtin(__builtin_amdgcn_permlane32_swap)
  i32x2 r = __builtin_amdgcn_permlane32_swap((int)a, (int)b, false, false);
  a = (u32)r[0]; b = (u32)r[1];
#else
  asm volatile("v_permlane32_swap_b32 %0, %1" : "+v"(a), "+v"(b));
#endif
}

__device__ __forceinline__ float xmaxf(float x) {
  u32 a = __float_as_uint(x), b = a;
  plswap(a, b);
  return fmaxf(__uint_as_float(a), __uint_as_float(b));
}
__device__ __forceinline__ float xaddf(float x) {
  u32 a = __float_as_uint(x), b = a;
  plswap(a, b);
  return __uint_as_float(a) + __uint_as_float(b);
}

__device__ __forceinline__ void gload16(const void* g,
                                        __attribute__((address_space(3))) void* l) {
  __builtin_amdgcn_global_load_lds((const __attribute__((address_space(1))) void*)g,
                                   l, 16, 0, 0);
}

// ---------------- convert fp32 -> bf16 (vectorized) ----------------
__global__ __launch_bounds__(256) void k_cvt_bf16(const float* __restrict__ in,
                                                  u16* __restrict__ out) {
  size_t i = (size_t)(blockIdx.x * blockDim.x + threadIdx.x) * 4;
  f32x4 f = *(const f32x4*)(in + i);
  u16x4 o;
  o[0] = f2bf(f[0]); o[1] = f2bf(f[1]); o[2] = f2bf(f[2]); o[3] = f2bf(f[3]);
  *(u16x4*)(out + i) = o;
}

// ---------------- transpose+convert: w[K][N] f32 -> wt[N][K] bf16 ----------------
__global__ __launch_bounds__(256) void k_transpose_bf16(const float* __restrict__ w,
                                                        u16* __restrict__ wt,
                                                        int K, int N) {
  __shared__ float t[32][33];
  int n0 = blockIdx.x * 32, k0 = blockIdx.y * 32;
  int tx = threadIdx.x & 31;
  int ty = threadIdx.x >> 5;   // 0..7
  #pragma unroll
  for (int r = 0; r < 4; ++r)
    t[ty + r*8][tx] = w[(size_t)(k0 + ty + r*8) * N + n0 + tx];
  __syncthreads();
  #pragma unroll
  for (int r = 0; r < 4; ++r)
    wt[(size_t)(n0 + ty + r*8) * K + k0 + tx] = f2bf(t[tx][ty + r*8]);
}

// ---------------- bf16 MFMA GEMM: 128x128 tile, BK=32, 4 waves ----------------
// A: [M][K] bf16 row-major.  Bt: [N][K] bf16 (B transposed).  EPI 0: qkv scatter, 1: f32 out.
// EPI 0: q scaled by QSCALE; q,k as [B,H,T,HD]; v transposed [B,H,HD,T].
template<int EPI>
__global__ __launch_bounds__(256) void k_gemm(const u16* __restrict__ A,
                                              const u16* __restrict__ Bt,
                                              const float* __restrict__ bias,
                                              void* __restrict__ outp,
                                              int K) {
  __shared__ __align__(16) u16 lA[128*32];
  __shared__ __align__(16) u16 lB[128*32];
  int tid = threadIdx.x;
  int wave = tid >> 6, lane = tid & 63;
  int wr = wave >> 1, wc = wave & 1;
  int lrow = lane & 15, lgrp = lane >> 4;
  int row0 = blockIdx.y * 128, col0 = blockIdx.x * 128;

  f32x4 zero = {0.f, 0.f, 0.f, 0.f};
  f32x4 acc[4][4];
  #pragma unroll
  for (int m = 0; m < 4; ++m)
    #pragma unroll
    for (int n = 0; n < 4; ++n) acc[m][n] = zero;

  for (int kt = 0; kt < K; kt += 32) {
    #pragma unroll
    for (int p = 0; p < 2; ++p) {
      int c = (wave*2 + p)*64 + lane;   // 16B chunk index in tile (0..511)
      int r = c >> 2, kc = c & 3;       // tile row, 16B chunk within row
      gload16(A  + (size_t)(row0 + r)*K + kt + kc*8,
              (__attribute__((address_space(3))) char*)lA + (wave*2 + p)*1024);
      gload16(Bt + (size_t)(col0 + r)*K + kt + kc*8,
              (__attribute__((address_space(3))) char*)lB + (wave*2 + p)*1024);
    }
    __syncthreads();
    bf16x8 af[4], bfr[4];
    #pragma unroll
    for (int m = 0; m < 4; ++m)
      af[m] = *(const bf16x8*)(lA + (wr*64 + m*16 + lrow)*32 + lgrp*8);
    #pragma unroll
    for (int n = 0; n < 4; ++n)
      bfr[n] = *(const bf16x8*)(lB + (wc*64 + n*16 + lrow)*32 + lgrp*8);
    #pragma unroll
    for (int m = 0; m < 4; ++m)
      #pragma unroll
      for (int n = 0; n < 4; ++n)
        acc[m][n] = __builtin_amdgcn_mfma_f32_16x16x32_bf16(af[m], bfr[n], acc[m][n], 0, 0, 0);
    __syncthreads();
  }

  #pragma unroll
  for (int m = 0; m < 4; ++m) {
    #pragma unroll
    for (int n = 0; n < 4; ++n) {
      int gcol = col0 + wc*64 + n*16 + lrow;
      float bv = bias[gcol];
      #pragma unroll
      for (int r = 0; r < 4; ++r) {
        int grow = row0 + wr*64 + m*16 + lgrp*4 + r;
        float val = acc[m][n][r] + bv;
        if (EPI == 0) {
          int which = gcol >> 10, c = gcol & 1023;
          int hh = c >> 6, d = c & 63;
          int bb = grow >> 11, tt = grow & 2047;
          if (which == 0) val *= QSCALE;   // fold softmax scale * log2(e) into q
          size_t idx;
          if (which == 2)   // V transposed: [B,H,HD,T]
            idx = 2*BHTD_ + ((size_t)(bb*H_ + hh)*HD_ + d)*T_ + tt;
          else              // Q,K: [B,H,T,HD]
            idx = (size_t)which*BHTD_ + ((size_t)(bb*H_ + hh)*T_ + tt)*HD_ + d;
          ((u16*)outp)[idx] = f2bf(val);
        } else {
          ((float*)outp)[(size_t)grow*C_ + gcol] = val;
        }
      }
    }
  }
}

// ---------------- causal flash attention: swapped-operand, in-register, K-prefetch ----------------
// 512 blocks x 4 waves. head = bid&63 (8 heads per XCD -> K/V L2/L3-resident).
// Wave owns strip pair (p, 63-p), 32 q-rows each: exactly 33 KV tiles per wave.
// T14 pipeline: K double-buffered in registers (tile t+1's K issued during tile t's
// softmax/PV); V single-buffered (issue-at-top -> use-at-PV covers its latency).
// ZERO LDS, zero barriers.
__global__ __launch_bounds__(256, 2) void k_attn(const u16* __restrict__ q,
                                                 const u16* __restrict__ k,
                                                 const u16* __restrict__ vt,
                                                 u16* __restrict__ y) {
  int tid = threadIdx.x;
  int wave = tid >> 6, lane = tid & 63;
  int l31 = lane & 31, hi = lane >> 5;
  int bid = blockIdx.x;
  int head = bid & 63;                    // bid&7 = head&7 -> stable XCD per head
  int pidx = (bid >> 6) * 4 + wave;       // 0..31
  int bidx = head >> 4, hh = head & 15;
  const u16* qb = q  + (size_t)head * T_ * HD_;
  const u16* kb = k  + (size_t)head * T_ * HD_;
  const u16* vb = vt + (size_t)head * HD_ * T_;   // [HD][T]

  f32x16 zero16 = {0.f,0.f,0.f,0.f,0.f,0.f,0.f,0.f,0.f,0.f,0.f,0.f,0.f,0.f,0.f,0.f};

  auto strip = [&](int s) {
    int qr0 = s * 32;
    const u16* qrow = qb + (size_t)(qr0 + l31)*HD_ + hi*8;
    bf16x8 qf0 = *(const bf16x8*)(qrow);
    bf16x8 qf1 = *(const bf16x8*)(qrow + 16);
    bf16x8 qf2 = *(const bf16x8*)(qrow + 32);
    bf16x8 qf3 = *(const bf16x8*)(qrow + 48);

    f32x16 od0 = zero16, od1 = zero16;
    float mrun = -1e30f, lrun = 0.f;
    int qg = qr0 + l31;

    auto loadK = [&](bf16x8 (&kf)[8], int kv0) {
      const u16* krow = kb + (size_t)(kv0 + l31)*HD_ + hi*8;
      #pragma unroll
      for (int i = 0; i < 4; ++i) kf[i] = *(const bf16x8*)(krow + 16*i);
      const u16* krow1 = krow + 32*HD_;
      #pragma unroll
      for (int i = 0; i < 4; ++i) kf[4+i] = *(const bf16x8*)(krow1 + 16*i);
    };

    // tile: compute with kf (already prefetched); prefetch kv0+64 into kn unless last.
    auto tile = [&](bf16x8 (&kf)[8], bf16x8 (&kn)[8], int kv0, bool last) {
      // --- V^T fragments issued first: use is after softmax (~900 cy away) ---
      bf16x8 vf[8];
      {
        const u16* vrow = vb + (size_t)l31*T_ + kv0 + hi*8;
        #pragma unroll
        for (int i = 0; i < 4; ++i) vf[i] = *(const bf16x8*)(vrow + 16*i);
        const u16* vrow1 = vrow + 32*T_;
        #pragma unroll
        for (int i = 0; i < 4; ++i) vf[4+i] = *(const bf16x8*)(vrow1 + 16*i);
      }

      // --- QK^T swapped: S^T[k][q], col = q = lane&31 (K was prefetched) ---
      f32x16 s0 = zero16, s1 = zero16;
      s0 = __builtin_amdgcn_mfma_f32_32x32x16_bf16(kf[0], qf0, s0, 0, 0, 0);
      s1 = __builtin_amdgcn_mfma_f32_32x32x16_bf16(kf[4], qf0, s1, 0, 0, 0);
      s0 = __builtin_amdgcn_mfma_f32_32x32x16_bf16(kf[1], qf1, s0, 0, 0, 0);
      s1 = __builtin_amdgcn_mfma_f32_32x32x16_bf16(kf[5], qf1, s1, 0, 0, 0);
      s0 = __builtin_amdgcn_mfma_f32_32x32x16_bf16(kf[2], qf2, s0, 0, 0, 0);
      s1 = __builtin_amdgcn_mfma_f32_32x32x16_bf16(kf[6], qf2, s1, 0, 0, 0);
      s0 = __builtin_amdgcn_mfma_f32_32x32x16_bf16(kf[3], qf3, s0, 0, 0, 0);
      s1 = __builtin_amdgcn_mfma_f32_32x32x16_bf16(kf[7], qf3, s1, 0, 0, 0);

      // --- prefetch next tile's K: consumer is next tile's QK^T (>1000 cy away) ---
      if (!last) loadK(kn, kv0 + 64);

      // --- causal mask (last tile only); k_local = (reg&3)+8*(reg>>2)+4*hi ---
      if (last) {
        #pragma unroll
        for (int r = 0; r < 16; ++r) {
          int kl = (r & 3) + 8*(r >> 2) + 4*hi;
          if (kv0 + kl      > qg) s0[r] = -1e30f;
          if (kv0 + 32 + kl > qg) s1[r] = -1e30f;
        }
      }

      // --- in-lane max tree + partner combine ---
      float t[16];
      #pragma unroll
      for (int i = 0; i < 16; ++i) t[i] = fmaxf(s0[i], s1[i]);
      #pragma unroll
      for (int off = 8; off > 0; off >>= 1)
        #pragma unroll
        for (int i = 0; i < 8; ++i)
          if (i < off) t[i] = fmaxf(t[i], t[i + off]);
      float pmax = xmaxf(t[0]);

      float mnew = fmaxf(mrun, pmax);
      float ex = EXP2(mrun - mnew);
      mrun = mnew;

      // --- exponentials (in-place) + sum ---
      #pragma unroll
      for (int i = 0; i < 16; ++i) s0[i] = EXP2(s0[i] - mnew);
      #pragma unroll
      for (int i = 0; i < 16; ++i) s1[i] = EXP2(s1[i] - mnew);
      float u[16];
      #pragma unroll
      for (int i = 0; i < 16; ++i) u[i] = s0[i] + s1[i];
      #pragma unroll
      for (int off = 8; off > 0; off >>= 1)
        #pragma unroll
        for (int i = 0; i < 8; ++i)
          if (i < off) u[i] = u[i] + u[i + off];
      float rsum = xaddf(u[0]);
      lrun = lrun * ex + rsum;

      // --- rescale O^T (in-lane: col = q) ---
      #pragma unroll
      for (int i = 0; i < 16; ++i) { od0[i] *= ex; od1[i] *= ex; }

      // --- build P fragments: v_cvt_pk_bf16_f32 + permlane32_swap (T12) ---
      bf16x8 pf0, pf1, pf2, pf3;
      {
        u32 a0 = cvtpk(s0[0], s0[1]),   a1 = cvtpk(s0[2], s0[3]);
        u32 b0 = cvtpk(s0[4], s0[5]),   b1 = cvtpk(s0[6], s0[7]);
        plswap(a0, b0); plswap(a1, b1);
        u32 wa[4] = {a0, a1, b0, b1};
        __builtin_memcpy(&pf0, wa, 16);
      }
      {
        u32 a0 = cvtpk(s0[8], s0[9]),   a1 = cvtpk(s0[10], s0[11]);
        u32 b0 = cvtpk(s0[12], s0[13]), b1 = cvtpk(s0[14], s0[15]);
        plswap(a0, b0); plswap(a1, b1);
        u32 wa[4] = {a0, a1, b0, b1};
        __builtin_memcpy(&pf1, wa, 16);
      }
      {
        u32 a0 = cvtpk(s1[0], s1[1]),   a1 = cvtpk(s1[2], s1[3]);
        u32 b0 = cvtpk(s1[4], s1[5]),   b1 = cvtpk(s1[6], s1[7]);
        plswap(a0, b0); plswap(a1, b1);
        u32 wa[4] = {a0, a1, b0, b1};
        __builtin_memcpy(&pf2, wa, 16);
      }
      {
        u32 a0 = cvtpk(s1[8], s1[9]),   a1 = cvtpk(s1[10], s1[11]);
        u32 b0 = cvtpk(s1[12], s1[13]), b1 = cvtpk(s1[14], s1[15]);
        plswap(a0, b0); plswap(a1, b1);
        u32 wa[4] = {a0, a1, b0, b1};
        __builtin_memcpy(&pf3, wa, 16);
      }

      // --- PV swapped: O^T[d][q] += V^T-frag x P-frag ---
      od0 = __builtin_amdgcn_mfma_f32_32x32x16_bf16(vf[0], pf0, od0, 0, 0, 0);
      od0 = __builtin_amdgcn_mfma_f32_32x32x16_bf16(vf[1], pf1, od0, 0, 0, 0);
      od0 = __builtin_amdgcn_mfma_f32_32x32x16_bf16(vf[2], pf2, od0, 0, 0, 0);
      od0 = __builtin_amdgcn_mfma_f32_32x32x16_bf16(vf[3], pf3, od0, 0, 0, 0);
      od1 = __builtin_amdgcn_mfma_f32_32x32x16_bf16(vf[4], pf0, od1, 0, 0, 0);
      od1 = __builtin_amdgcn_mfma_f32_32x32x16_bf16(vf[5], pf1, od1, 0, 0, 0);
      od1 = __builtin_amdgcn_mfma_f32_32x32x16_bf16(vf[6], pf2, od1, 0, 0, 0);
      od1 = __builtin_amdgcn_mfma_f32_32x32x16_bf16(vf[7], pf3, od1, 0, 0, 0);
    };

    int nt = (s >> 1) + 1;
    bf16x8 kA[8], kB[8];
    loadK(kA, 0);
    int kt = 0;
    for (;;) {
      bool last = (kt == nt - 1);
      tile(kA, kB, kt*64, last);
      if (last) break;
      ++kt;
      last = (kt == nt - 1);
      tile(kB, kA, kt*64, last);
      if (last) break;
      ++kt;
    }

    // --- epilogue: y[B,T,C] bf16; row = qr0+l31, d = d0*32 + (2r&3)+8*(r>>1)+4*hi ---
    float inv = 1.0f / lrun;
    u16* yrow = y + ((size_t)(bidx*T_) + qr0 + l31)*C_ + hh*64;
    #pragma unroll
    for (int r = 0; r < 8; ++r) {
      int dp = ((2*r) & 3) + 8*(r >> 1) + 4*hi;
      u32 w0 = cvtpk(od0[2*r]*inv, od0[2*r+1]*inv);
      u32 w1 = cvtpk(od1[2*r]*inv, od1[2*r+1]*inv);
      *(u32*)(yrow + dp)      = w0;
      *(u32*)(yrow + 32 + dp) = w1;
    }
  };

  strip(pidx);
  strip(63 - pidx);
}

extern "C" void kernel_launch(void* const* d_in, const int* in_sizes, int n_in,
                              void* d_out, int out_size, void* d_ws, size_t ws_size,
                              hipStream_t stream) {
  const float* x      = (const float*)d_in[0];
  const float* w_attn = (const float*)d_in[1];
  const float* b_attn = (const float*)d_in[2];
  const float* w_proj = (const float*)d_in[3];
  const float* b_proj = (const float*)d_in[4];

  char* ws = (char*)d_ws;
  size_t off = 0;
  auto walloc = [&](size_t bytes) -> void* {
    void* p = ws + off;
    off += (bytes + 255) & ~(size_t)255;
    return p;
  };
  u16* xbf = (u16*)walloc((size_t)BT_ * C_ * 2);      // x as bf16; later reused as y
  u16* wat = (u16*)walloc((size_t)C3_ * C_ * 2);      // w_attn^T bf16 [3C][C]
  u16* wpt = (u16*)walloc((size_t)C_ * C_ * 2);       // w_proj^T bf16 [C][C]
  u16* qkv = (u16*)walloc(3 * BHTD_ * 2);             // q,k [B,H,T,HD]; v [B,H,HD,T]
  u16* qp = qkv;
  u16* kp = qkv + BHTD_;
  u16* vp = qkv + 2*BHTD_;
  u16* ybf = xbf;   // alias: x consumed by GEMM1 before attention writes y

  k_cvt_bf16<<<(BT_*C_)/1024, 256, 0, stream>>>(x, xbf);
  k_transpose_bf16<<<dim3(C3_/32, C_/32), 256, 0, stream>>>(w_attn, wat, C_, C3_);
  k_transpose_bf16<<<dim3(C_/32, C_/32), 256, 0, stream>>>(w_proj, wpt, C_, C_);
  k_gemm<0><<<dim3(C3_/128, BT_/128), 256, 0, stream>>>(xbf, wat, b_attn, (void*)qkv, C_);
  k_attn<<<dim3(512), 256, 0, stream>>>(qp, kp, vp, ybf);
  k_gemm<1><<<dim3(C_/128, BT_/128), 256, 0, stream>>>(ybf, wpt, b_proj, d_out, C_);
}

// Round 9
// 215.373 us; speedup vs baseline: 2.0254x; 1.2141x over previous
//
#include <hip/hip_runtime.h>
#include <hip/hip_bf16.h>

#define B_ 4
#define T_ 2048
#define C_ 1024
#define H_ 16
#define HD_ 64
#define BT_ (B_*T_)            // 8192
#define C3_ (3*C_)             // 3072
#define BHTD_ ((size_t)B_*H_*T_*HD_)  // 8388608 elements per q/k/v

// softmax scale 1/8 with log2(e) folded in (attention uses exp2)
#define QSCALE 0.18033688011112042f

using u16 = unsigned short;
using u32 = unsigned int;
using bf16x8 = __attribute__((ext_vector_type(8))) short;
using f32x4  = __attribute__((ext_vector_type(4))) float;
using f32x16 = __attribute__((ext_vector_type(16))) float;
using u16x4  = __attribute__((ext_vector_type(4))) u16;
typedef int i32x2 __attribute__((ext_vector_type(2)));

#if __has_builtin(__builtin_amdgcn_exp2f)
#define EXP2(x) __builtin_amdgcn_exp2f(x)
#else
#define EXP2(x) exp2f(x)
#endif

__device__ __forceinline__ u16 f2bf(float f) {
  u32 u = __float_as_uint(f);
  u += 0x7fffu + ((u >> 16) & 1u);   // round-to-nearest-even
  return (u16)(u >> 16);
}

// v_cvt_pk_bf16_f32: one instruction packs two f32 -> two bf16 (RTNE)
__device__ __forceinline__ u32 cvtpk(float lo, float hi) {
  u32 r;
  asm("v_cvt_pk_bf16_f32 %0, %1, %2" : "=v"(r) : "v"(lo), "v"(hi));
  return r;
}

// exchange with the lane^32 partner
__device__ __forceinline__ void plswap(u32 &a, u32 &b) {
#if __has_builtin(__builtin_amdgcn_permlane32_swap)
  i32x2 r = __builtin_amdgcn_permlane32_swap((int)a, (int)b, false, false);
  a = (u32)r[0]; b = (u32)r[1];
#else
  asm volatile("v_permlane32_swap_b32 %0, %1" : "+v"(a), "+v"(b));
#endif
}

__device__ __forceinline__ float xmaxf(float x) {
  u32 a = __float_as_uint(x), b = a;
  plswap(a, b);
  return fmaxf(__uint_as_float(a), __uint_as_float(b));
}
__device__ __forceinline__ float xaddf(float x) {
  u32 a = __float_as_uint(x), b = a;
  plswap(a, b);
  return __uint_as_float(a) + __uint_as_float(b);
}

__device__ __forceinline__ void gload16(const void* g,
                                        __attribute__((address_space(3))) void* l) {
  __builtin_amdgcn_global_load_lds((const __attribute__((address_space(1))) void*)g,
                                   l, 16, 0, 0);
}

// ---------------- convert fp32 -> bf16 (vectorized) ----------------
__global__ __launch_bounds__(256) void k_cvt_bf16(const float* __restrict__ in,
                                                  u16* __restrict__ out) {
  size_t i = (size_t)(blockIdx.x * blockDim.x + threadIdx.x) * 4;
  f32x4 f = *(const f32x4*)(in + i);
  u16x4 o;
  o[0] = f2bf(f[0]); o[1] = f2bf(f[1]); o[2] = f2bf(f[2]); o[3] = f2bf(f[3]);
  *(u16x4*)(out + i) = o;
}

// ---------------- transpose+convert: w[K][N] f32 -> wt[N][K] bf16 ----------------
__global__ __launch_bounds__(256) void k_transpose_bf16(const float* __restrict__ w,
                                                        u16* __restrict__ wt,
                                                        int K, int N) {
  __shared__ float t[32][33];
  int n0 = blockIdx.x * 32, k0 = blockIdx.y * 32;
  int tx = threadIdx.x & 31;
  int ty = threadIdx.x >> 5;   // 0..7
  #pragma unroll
  for (int r = 0; r < 4; ++r)
    t[ty + r*8][tx] = w[(size_t)(k0 + ty + r*8) * N + n0 + tx];
  __syncthreads();
  #pragma unroll
  for (int r = 0; r < 4; ++r)
    wt[(size_t)(n0 + ty + r*8) * K + k0 + tx] = f2bf(t[tx][ty + r*8]);
}

// ---------------- bf16 MFMA GEMM: 128x128 tile, BK=32, 4 waves ----------------
// A: [M][K] bf16 row-major.  Bt: [N][K] bf16 (B transposed).  EPI 0: qkv scatter, 1: f32 out.
// EPI 0: q scaled by QSCALE; q,k as [B,H,T,HD]; v transposed [B,H,HD,T].
template<int EPI>
__global__ __launch_bounds__(256) void k_gemm(const u16* __restrict__ A,
                                              const u16* __restrict__ Bt,
                                              const float* __restrict__ bias,
                                              void* __restrict__ outp,
                                              int K) {
  __shared__ __align__(16) u16 lA[128*32];
  __shared__ __align__(16) u16 lB[128*32];
  int tid = threadIdx.x;
  int wave = tid >> 6, lane = tid & 63;
  int wr = wave >> 1, wc = wave & 1;
  int lrow = lane & 15, lgrp = lane >> 4;
  int row0 = blockIdx.y * 128, col0 = blockIdx.x * 128;

  f32x4 zero = {0.f, 0.f, 0.f, 0.f};
  f32x4 acc[4][4];
  #pragma unroll
  for (int m = 0; m < 4; ++m)
    #pragma unroll
    for (int n = 0; n < 4; ++n) acc[m][n] = zero;

  for (int kt = 0; kt < K; kt += 32) {
    #pragma unroll
    for (int p = 0; p < 2; ++p) {
      int c = (wave*2 + p)*64 + lane;   // 16B chunk index in tile (0..511)
      int r = c >> 2, kc = c & 3;       // tile row, 16B chunk within row
      gload16(A  + (size_t)(row0 + r)*K + kt + kc*8,
              (__attribute__((address_space(3))) char*)lA + (wave*2 + p)*1024);
      gload16(Bt + (size_t)(col0 + r)*K + kt + kc*8,
              (__attribute__((address_space(3))) char*)lB + (wave*2 + p)*1024);
    }
    __syncthreads();
    bf16x8 af[4], bfr[4];
    #pragma unroll
    for (int m = 0; m < 4; ++m)
      af[m] = *(const bf16x8*)(lA + (wr*64 + m*16 + lrow)*32 + lgrp*8);
    #pragma unroll
    for (int n = 0; n < 4; ++n)
      bfr[n] = *(const bf16x8*)(lB + (wc*64 + n*16 + lrow)*32 + lgrp*8);
    #pragma unroll
    for (int m = 0; m < 4; ++m)
      #pragma unroll
      for (int n = 0; n < 4; ++n)
        acc[m][n] = __builtin_amdgcn_mfma_f32_16x16x32_bf16(af[m], bfr[n], acc[m][n], 0, 0, 0);
    __syncthreads();
  }

  #pragma unroll
  for (int m = 0; m < 4; ++m) {
    #pragma unroll
    for (int n = 0; n < 4; ++n) {
      int gcol = col0 + wc*64 + n*16 + lrow;
      float bv = bias[gcol];
      #pragma unroll
      for (int r = 0; r < 4; ++r) {
        int grow = row0 + wr*64 + m*16 + lgrp*4 + r;
        float val = acc[m][n][r] + bv;
        if (EPI == 0) {
          int which = gcol >> 10, c = gcol & 1023;
          int hh = c >> 6, d = c & 63;
          int bb = grow >> 11, tt = grow & 2047;
          if (which == 0) val *= QSCALE;   // fold softmax scale * log2(e) into q
          size_t idx;
          if (which == 2)   // V transposed: [B,H,HD,T]
            idx = 2*BHTD_ + ((size_t)(bb*H_ + hh)*HD_ + d)*T_ + tt;
          else              // Q,K: [B,H,T,HD]
            idx = (size_t)which*BHTD_ + ((size_t)(bb*H_ + hh)*T_ + tt)*HD_ + d;
          ((u16*)outp)[idx] = f2bf(val);
        } else {
          ((float*)outp)[(size_t)grow*C_ + gcol] = val;
        }
      }
    }
  }
}

// ---------------- causal flash attention: swapped-operand, in-register, 64-row Q-block ----------------
// Reverted to the round-5 (passing) no-LDS structure, upgraded with Q-blocking:
// each wave owns a 64-row strip s and computes TWO 32-row S-halves per K/V tile,
// reusing the same K/V fragments twice -> K/V global traffic HALVES vs round 5.
// Strip mapping is complementary across the grid halves (bid and bid+256 carry
// strips s and 31-s) so co-resident block pairs sum to ~constant work per SIMD.
// head = bid&63 keeps 8-heads-per-XCD L2 grouping. ZERO LDS, zero barriers.
__global__ __launch_bounds__(256, 2) void k_attn(const u16* __restrict__ q,
                                                 const u16* __restrict__ k,
                                                 const u16* __restrict__ vt,
                                                 u16* __restrict__ y) {
  int tid = threadIdx.x;
  int wave = tid >> 6, lane = tid & 63;
  int l31 = lane & 31, hi = lane >> 5;
  int bid = blockIdx.x;
  int head = bid & 63;                    // bid&7 = head&7 -> stable XCD group per head
  int g = bid >> 6;                       // 0..7
  int s = (g < 4) ? (g*4 + wave) : (31 - (g - 4)*4 - wave);   // 64-row strip 0..31
  int bidx = head >> 4, hh = head & 15;
  const u16* qb = q  + (size_t)head * T_ * HD_;
  const u16* kb = k  + (size_t)head * T_ * HD_;
  const u16* vb = vt + (size_t)head * HD_ * T_;   // [HD][T]

  f32x16 zero16 = {0.f,0.f,0.f,0.f,0.f,0.f,0.f,0.f,0.f,0.f,0.f,0.f,0.f,0.f,0.f,0.f};

  int qr0 = s * 64;
  // Q fragments for both 32-row halves, held for the whole kernel
  bf16x8 qfA[4], qfB[4];
  {
    const u16* qrowA = qb + (size_t)(qr0 + l31)*HD_ + hi*8;
    const u16* qrowB = qrowA + 32*HD_;
    #pragma unroll
    for (int i = 0; i < 4; ++i) { qfA[i] = *(const bf16x8*)(qrowA + 16*i);
                                  qfB[i] = *(const bf16x8*)(qrowB + 16*i); }
  }

  f32x16 oA0 = zero16, oA1 = zero16, oB0 = zero16, oB1 = zero16;
  float mrunA = -1e30f, lrunA = 0.f, mrunB = -1e30f, lrunB = 0.f;
  int qgA = qr0 + l31, qgB = qr0 + 32 + l31;

  // one 32-row half against one 64-row K/V tile (r5-validated body)
  auto halfstep = [&](bf16x8 (&qf)[4], f32x16 &od0, f32x16 &od1,
                      float &mrun, float &lrun, int qg, int kv0, bool domask,
                      bf16x8 (&kf)[8], bf16x8 (&vf)[8]) {
    // --- QK^T swapped: S^T[k][q], col = q = lane&31 ---
    f32x16 s0 = zero16, s1 = zero16;
    s0 = __builtin_amdgcn_mfma_f32_32x32x16_bf16(kf[0], qf[0], s0, 0, 0, 0);
    s1 = __builtin_amdgcn_mfma_f32_32x32x16_bf16(kf[4], qf[0], s1, 0, 0, 0);
    s0 = __builtin_amdgcn_mfma_f32_32x32x16_bf16(kf[1], qf[1], s0, 0, 0, 0);
    s1 = __builtin_amdgcn_mfma_f32_32x32x16_bf16(kf[5], qf[1], s1, 0, 0, 0);
    s0 = __builtin_amdgcn_mfma_f32_32x32x16_bf16(kf[2], qf[2], s0, 0, 0, 0);
    s1 = __builtin_amdgcn_mfma_f32_32x32x16_bf16(kf[6], qf[2], s1, 0, 0, 0);
    s0 = __builtin_amdgcn_mfma_f32_32x32x16_bf16(kf[3], qf[3], s0, 0, 0, 0);
    s1 = __builtin_amdgcn_mfma_f32_32x32x16_bf16(kf[7], qf[3], s1, 0, 0, 0);

    // --- causal mask (diagonal tile only); k_local = (reg&3)+8*(reg>>2)+4*hi ---
    if (domask) {
      #pragma unroll
      for (int r = 0; r < 16; ++r) {
        int kl = (r & 3) + 8*(r >> 2) + 4*hi;
        if (kv0 + kl      > qg) s0[r] = -1e30f;
        if (kv0 + 32 + kl > qg) s1[r] = -1e30f;
      }
    }

    // --- in-lane max tree + partner combine ---
    float t[16];
    #pragma unroll
    for (int i = 0; i < 16; ++i) t[i] = fmaxf(s0[i], s1[i]);
    #pragma unroll
    for (int off = 8; off > 0; off >>= 1)
      #pragma unroll
      for (int i = 0; i < 8; ++i)
        if (i < off) t[i] = fmaxf(t[i], t[i + off]);
    float pmax = xmaxf(t[0]);

    float mnew = fmaxf(mrun, pmax);
    float ex = EXP2(mrun - mnew);
    mrun = mnew;

    // --- exponentials + sum ---
    #pragma unroll
    for (int i = 0; i < 16; ++i) s0[i] = EXP2(s0[i] - mnew);
    #pragma unroll
    for (int i = 0; i < 16; ++i) s1[i] = EXP2(s1[i] - mnew);
    float u[16];
    #pragma unroll
    for (int i = 0; i < 16; ++i) u[i] = s0[i] + s1[i];
    #pragma unroll
    for (int off = 8; off > 0; off >>= 1)
      #pragma unroll
      for (int i = 0; i < 8; ++i)
        if (i < off) u[i] = u[i] + u[i + off];
    float rsum = xaddf(u[0]);
    lrun = lrun * ex + rsum;

    // --- rescale O^T (in-lane: col = q) ---
    #pragma unroll
    for (int i = 0; i < 16; ++i) { od0[i] *= ex; od1[i] *= ex; }

    // --- P fragments: v_cvt_pk_bf16_f32 + permlane32_swap (T12) ---
    bf16x8 pf0, pf1, pf2, pf3;
    {
      u32 a0 = cvtpk(s0[0], s0[1]),   a1 = cvtpk(s0[2], s0[3]);
      u32 b0 = cvtpk(s0[4], s0[5]),   b1 = cvtpk(s0[6], s0[7]);
      plswap(a0, b0); plswap(a1, b1);
      u32 wa[4] = {a0, a1, b0, b1};
      __builtin_memcpy(&pf0, wa, 16);
    }
    {
      u32 a0 = cvtpk(s0[8], s0[9]),   a1 = cvtpk(s0[10], s0[11]);
      u32 b0 = cvtpk(s0[12], s0[13]), b1 = cvtpk(s0[14], s0[15]);
      plswap(a0, b0); plswap(a1, b1);
      u32 wa[4] = {a0, a1, b0, b1};
      __builtin_memcpy(&pf1, wa, 16);
    }
    {
      u32 a0 = cvtpk(s1[0], s1[1]),   a1 = cvtpk(s1[2], s1[3]);
      u32 b0 = cvtpk(s1[4], s1[5]),   b1 = cvtpk(s1[6], s1[7]);
      plswap(a0, b0); plswap(a1, b1);
      u32 wa[4] = {a0, a1, b0, b1};
      __builtin_memcpy(&pf2, wa, 16);
    }
    {
      u32 a0 = cvtpk(s1[8], s1[9]),   a1 = cvtpk(s1[10], s1[11]);
      u32 b0 = cvtpk(s1[12], s1[13]), b1 = cvtpk(s1[14], s1[15]);
      plswap(a0, b0); plswap(a1, b1);
      u32 wa[4] = {a0, a1, b0, b1};
      __builtin_memcpy(&pf3, wa, 16);
    }

    // --- PV swapped: O^T[d][q] += V^T-frag x P-frag ---
    od0 = __builtin_amdgcn_mfma_f32_32x32x16_bf16(vf[0], pf0, od0, 0, 0, 0);
    od0 = __builtin_amdgcn_mfma_f32_32x32x16_bf16(vf[1], pf1, od0, 0, 0, 0);
    od0 = __builtin_amdgcn_mfma_f32_32x32x16_bf16(vf[2], pf2, od0, 0, 0, 0);
    od0 = __builtin_amdgcn_mfma_f32_32x32x16_bf16(vf[3], pf3, od0, 0, 0, 0);
    od1 = __builtin_amdgcn_mfma_f32_32x32x16_bf16(vf[4], pf0, od1, 0, 0, 0);
    od1 = __builtin_amdgcn_mfma_f32_32x32x16_bf16(vf[5], pf1, od1, 0, 0, 0);
    od1 = __builtin_amdgcn_mfma_f32_32x32x16_bf16(vf[6], pf2, od1, 0, 0, 0);
    od1 = __builtin_amdgcn_mfma_f32_32x32x16_bf16(vf[7], pf3, od1, 0, 0, 0);
  };

  for (int t = 0; t <= s; ++t) {
    int kv0 = t*64;
    bool last = (t == s);

    // --- K fragments (rows kv0+l31, kv0+32+l31) ---
    bf16x8 kf[8], vf[8];
    {
      const u16* krow = kb + (size_t)(kv0 + l31)*HD_ + hi*8;
      const u16* krow1 = krow + 32*HD_;
      #pragma unroll
      for (int i = 0; i < 4; ++i) { kf[i] = *(const bf16x8*)(krow + 16*i);
                                    kf[4+i] = *(const bf16x8*)(krow1 + 16*i); }
      // --- V^T fragments issued early; first use is after half-A softmax ---
      const u16* vrow = vb + (size_t)l31*T_ + kv0 + hi*8;
      const u16* vrow1 = vrow + 32*T_;
      #pragma unroll
      for (int i = 0; i < 4; ++i) { vf[i] = *(const bf16x8*)(vrow + 16*i);
                                    vf[4+i] = *(const bf16x8*)(vrow1 + 16*i); }
    }

    halfstep(qfA, oA0, oA1, mrunA, lrunA, qgA, kv0, last, kf, vf);
    halfstep(qfB, oB0, oB1, mrunB, lrunB, qgB, kv0, last, kf, vf);
  }

  // --- epilogue: y[B,T,C] bf16; d = d0*32 + (2r&3)+8*(r>>1)+4*hi ---
  {
    float inv = 1.0f / lrunA;
    u16* yrow = y + ((size_t)(bidx*T_) + qr0 + l31)*C_ + hh*64;
    #pragma unroll
    for (int r = 0; r < 8; ++r) {
      int dp = ((2*r) & 3) + 8*(r >> 1) + 4*hi;
      *(u32*)(yrow + dp)      = cvtpk(oA0[2*r]*inv, oA0[2*r+1]*inv);
      *(u32*)(yrow + 32 + dp) = cvtpk(oA1[2*r]*inv, oA1[2*r+1]*inv);
    }
  }
  {
    float inv = 1.0f / lrunB;
    u16* yrow = y + ((size_t)(bidx*T_) + qr0 + 32 + l31)*C_ + hh*64;
    #pragma unroll
    for (int r = 0; r < 8; ++r) {
      int dp = ((2*r) & 3) + 8*(r >> 1) + 4*hi;
      *(u32*)(yrow + dp)      = cvtpk(oB0[2*r]*inv, oB0[2*r+1]*inv);
      *(u32*)(yrow + 32 + dp) = cvtpk(oB1[2*r]*inv, oB1[2*r+1]*inv);
    }
  }
}

extern "C" void kernel_launch(void* const* d_in, const int* in_sizes, int n_in,
                              void* d_out, int out_size, void* d_ws, size_t ws_size,
                              hipStream_t stream) {
  const float* x      = (const float*)d_in[0];
  const float* w_attn = (const float*)d_in[1];
  const float* b_attn = (const float*)d_in[2];
  const float* w_proj = (const float*)d_in[3];
  const float* b_proj = (const float*)d_in[4];

  char* ws = (char*)d_ws;
  size_t off = 0;
  auto walloc = [&](size_t bytes) -> void* {
    void* p = ws + off;
    off += (bytes + 255) & ~(size_t)255;
    return p;
  };
  u16* xbf = (u16*)walloc((size_t)BT_ * C_ * 2);      // x as bf16; later reused as y
  u16* wat = (u16*)walloc((size_t)C3_ * C_ * 2);      // w_attn^T bf16 [3C][C]
  u16* wpt = (u16*)walloc((size_t)C_ * C_ * 2);       // w_proj^T bf16 [C][C]
  u16* qkv = (u16*)walloc(3 * BHTD_ * 2);             // q,k [B,H,T,HD]; v [B,H,HD,T]
  u16* qp = qkv;
  u16* kp = qkv + BHTD_;
  u16* vp = qkv + 2*BHTD_;
  u16* ybf = xbf;   // alias: x consumed by GEMM1 before attention writes y

  k_cvt_bf16<<<(BT_*C_)/1024, 256, 0, stream>>>(x, xbf);
  k_transpose_bf16<<<dim3(C3_/32, C_/32), 256, 0, stream>>>(w_attn, wat, C_, C3_);
  k_transpose_bf16<<<dim3(C_/32, C_/32), 256, 0, stream>>>(w_proj, wpt, C_, C_);
  k_gemm<0><<<dim3(C3_/128, BT_/128), 256, 0, stream>>>(xbf, wat, b_attn, (void*)qkv, C_);
  k_attn<<<dim3(512), 256, 0, stream>>>(qp, kp, vp, ybf);
  k_gemm<1><<<dim3(C_/128, BT_/128), 256, 0, stream>>>(ybf, wpt, b_proj, d_out, C_);
}

// Round 10
// 200.728 us; speedup vs baseline: 2.1732x; 1.0730x over previous
//
#include <hip/hip_runtime.h>
#include <hip/hip_bf16.h>

#define B_ 4
#define T_ 2048
#define C_ 1024
#define H_ 16
#define HD_ 64
#define BT_ (B_*T_)            // 8192
#define C3_ (3*C_)             // 3072
#define BHTD_ ((size_t)B_*H_*T_*HD_)  // 8388608 elements per q/k/v

// softmax scale 1/8 with log2(e) folded in (attention uses exp2)
#define QSCALE 0.18033688011112042f

using u16 = unsigned short;
using u32 = unsigned int;
using bf16x8 = __attribute__((ext_vector_type(8))) short;
using f32x4  = __attribute__((ext_vector_type(4))) float;
using f32x16 = __attribute__((ext_vector_type(16))) float;
using u16x4  = __attribute__((ext_vector_type(4))) u16;
typedef int i32x2 __attribute__((ext_vector_type(2)));

#if __has_builtin(__builtin_amdgcn_exp2f)
#define EXP2(x) __builtin_amdgcn_exp2f(x)
#else
#define EXP2(x) exp2f(x)
#endif

__device__ __forceinline__ u16 f2bf(float f) {
  u32 u = __float_as_uint(f);
  u += 0x7fffu + ((u >> 16) & 1u);   // round-to-nearest-even
  return (u16)(u >> 16);
}

// v_cvt_pk_bf16_f32: one instruction packs two f32 -> two bf16 (RTNE)
__device__ __forceinline__ u32 cvtpk(float lo, float hi) {
  u32 r;
  asm("v_cvt_pk_bf16_f32 %0, %1, %2" : "=v"(r) : "v"(lo), "v"(hi));
  return r;
}

// exchange with the lane^32 partner
__device__ __forceinline__ void plswap(u32 &a, u32 &b) {
#if __has_builtin(__builtin_amdgcn_permlane32_swap)
  i32x2 r = __builtin_amdgcn_permlane32_swap((int)a, (int)b, false, false);
  a = (u32)r[0]; b = (u32)r[1];
#else
  asm volatile("v_permlane32_swap_b32 %0, %1" : "+v"(a), "+v"(b));
#endif
}

__device__ __forceinline__ float xmaxf(float x) {
  u32 a = __float_as_uint(x), b = a;
  plswap(a, b);
  return fmaxf(__uint_as_float(a), __uint_as_float(b));
}
__device__ __forceinline__ float xaddf(float x) {
  u32 a = __float_as_uint(x), b = a;
  plswap(a, b);
  return __uint_as_float(a) + __uint_as_float(b);
}

__device__ __forceinline__ void gload16(const void* g,
                                        __attribute__((address_space(3))) void* l) {
  __builtin_amdgcn_global_load_lds((const __attribute__((address_space(1))) void*)g,
                                   l, 16, 0, 0);
}

// ---------------- convert fp32 -> bf16 (vectorized) ----------------
__global__ __launch_bounds__(256) void k_cvt_bf16(const float* __restrict__ in,
                                                  u16* __restrict__ out) {
  size_t i = (size_t)(blockIdx.x * blockDim.x + threadIdx.x) * 4;
  f32x4 f = *(const f32x4*)(in + i);
  u16x4 o;
  o[0] = f2bf(f[0]); o[1] = f2bf(f[1]); o[2] = f2bf(f[2]); o[3] = f2bf(f[3]);
  *(u16x4*)(out + i) = o;
}

// ---------------- transpose+convert: w[K][N] f32 -> wt[N][K] bf16 ----------------
__global__ __launch_bounds__(256) void k_transpose_bf16(const float* __restrict__ w,
                                                        u16* __restrict__ wt,
                                                        int K, int N) {
  __shared__ float t[32][33];
  int n0 = blockIdx.x * 32, k0 = blockIdx.y * 32;
  int tx = threadIdx.x & 31;
  int ty = threadIdx.x >> 5;   // 0..7
  #pragma unroll
  for (int r = 0; r < 4; ++r)
    t[ty + r*8][tx] = w[(size_t)(k0 + ty + r*8) * N + n0 + tx];
  __syncthreads();
  #pragma unroll
  for (int r = 0; r < 4; ++r)
    wt[(size_t)(n0 + ty + r*8) * K + k0 + tx] = f2bf(t[tx][ty + r*8]);
}

// ---------------- transpose V: [B,H,T,HD] u16 -> [B,H,HD,T] u16 ----------------
// 64x64 tiles through LDS (validated k_transpose pattern); grid (T/64, B*H).
__global__ __launch_bounds__(256) void k_transpose_v(const u16* __restrict__ src,
                                                     u16* __restrict__ dst) {
  __shared__ u16 t[64][72];   // row stride 144B (multiple of 16B), padded vs banks
  int bh = blockIdx.y;
  int t0 = blockIdx.x * 64;
  const u16* s = src + (size_t)bh * T_ * HD_;
  u16* d = dst + (size_t)bh * HD_ * T_;
  int r = threadIdx.x >> 2, c0 = (threadIdx.x & 3) * 16;
  bf16x8 a0 = *(const bf16x8*)(s + (size_t)(t0 + r)*HD_ + c0);
  bf16x8 a1 = *(const bf16x8*)(s + (size_t)(t0 + r)*HD_ + c0 + 8);
  #pragma unroll
  for (int j = 0; j < 8; ++j) t[r][c0 + j] = (u16)a0[j];
  #pragma unroll
  for (int j = 0; j < 8; ++j) t[r][c0 + 8 + j] = (u16)a1[j];
  __syncthreads();
  bf16x8 b0, b1;
  #pragma unroll
  for (int j = 0; j < 8; ++j) b0[j] = (short)t[c0 + j][r];
  #pragma unroll
  for (int j = 0; j < 8; ++j) b1[j] = (short)t[c0 + 8 + j][r];
  *(bf16x8*)(d + (size_t)r*T_ + t0 + c0) = b0;
  *(bf16x8*)(d + (size_t)r*T_ + t0 + c0 + 8) = b1;
}

// ---------------- bf16 MFMA GEMM: 128x128 tile, BK=32, 4 waves ----------------
// A: [M][K] bf16 row-major.  Bt: [N][K] bf16 (B transposed).  EPI 0: qkv, 1: f32 out.
// EPI 0: q scaled by QSCALE; q,k -> outp as [B,H,T,HD]; v -> outp2 as [B,H,T,HD]
// (coalesced; the V transpose is a separate kernel -- the per-element column
// scatter into [B,H,HD,T] was costing ~26us of store serialization here).
template<int EPI>
__global__ __launch_bounds__(256) void k_gemm(const u16* __restrict__ A,
                                              const u16* __restrict__ Bt,
                                              const float* __restrict__ bias,
                                              void* __restrict__ outp,
                                              void* __restrict__ outp2,
                                              int K) {
  __shared__ __align__(16) u16 lA[128*32];
  __shared__ __align__(16) u16 lB[128*32];
  int tid = threadIdx.x;
  int wave = tid >> 6, lane = tid & 63;
  int wr = wave >> 1, wc = wave & 1;
  int lrow = lane & 15, lgrp = lane >> 4;
  int row0 = blockIdx.y * 128, col0 = blockIdx.x * 128;

  f32x4 zero = {0.f, 0.f, 0.f, 0.f};
  f32x4 acc[4][4];
  #pragma unroll
  for (int m = 0; m < 4; ++m)
    #pragma unroll
    for (int n = 0; n < 4; ++n) acc[m][n] = zero;

  for (int kt = 0; kt < K; kt += 32) {
    #pragma unroll
    for (int p = 0; p < 2; ++p) {
      int c = (wave*2 + p)*64 + lane;   // 16B chunk index in tile (0..511)
      int r = c >> 2, kc = c & 3;       // tile row, 16B chunk within row
      gload16(A  + (size_t)(row0 + r)*K + kt + kc*8,
              (__attribute__((address_space(3))) char*)lA + (wave*2 + p)*1024);
      gload16(Bt + (size_t)(col0 + r)*K + kt + kc*8,
              (__attribute__((address_space(3))) char*)lB + (wave*2 + p)*1024);
    }
    __syncthreads();
    bf16x8 af[4], bfr[4];
    #pragma unroll
    for (int m = 0; m < 4; ++m)
      af[m] = *(const bf16x8*)(lA + (wr*64 + m*16 + lrow)*32 + lgrp*8);
    #pragma unroll
    for (int n = 0; n < 4; ++n)
      bfr[n] = *(const bf16x8*)(lB + (wc*64 + n*16 + lrow)*32 + lgrp*8);
    #pragma unroll
    for (int m = 0; m < 4; ++m)
      #pragma unroll
      for (int n = 0; n < 4; ++n)
        acc[m][n] = __builtin_amdgcn_mfma_f32_16x16x32_bf16(af[m], bfr[n], acc[m][n], 0, 0, 0);
    __syncthreads();
  }

  #pragma unroll
  for (int m = 0; m < 4; ++m) {
    #pragma unroll
    for (int n = 0; n < 4; ++n) {
      int gcol = col0 + wc*64 + n*16 + lrow;
      float bv = bias[gcol];
      #pragma unroll
      for (int r = 0; r < 4; ++r) {
        int grow = row0 + wr*64 + m*16 + lgrp*4 + r;
        float val = acc[m][n][r] + bv;
        if (EPI == 0) {
          int which = gcol >> 10, c = gcol & 1023;
          int hh = c >> 6, d = c & 63;
          int bb = grow >> 11, tt = grow & 2047;
          if (which == 0) val *= QSCALE;   // fold softmax scale * log2(e) into q
          size_t idx = ((size_t)(bb*H_ + hh)*T_ + tt)*HD_ + d;   // [B,H,T,HD]
          if (which == 2)
            ((u16*)outp2)[idx] = f2bf(val);            // V (untransposed, coalesced)
          else
            ((u16*)outp)[(size_t)which*BHTD_ + idx] = f2bf(val); // Q, K
        } else {
          ((float*)outp)[(size_t)grow*C_ + gcol] = val;
        }
      }
    }
  }
}

// ---------------- causal flash attention: swapped-operand, in-register, 64-row Q-block ----------------
// (unchanged from round 9 -- validated, ~61us steady state)
__global__ __launch_bounds__(256, 2) void k_attn(const u16* __restrict__ q,
                                                 const u16* __restrict__ k,
                                                 const u16* __restrict__ vt,
                                                 u16* __restrict__ y) {
  int tid = threadIdx.x;
  int wave = tid >> 6, lane = tid & 63;
  int l31 = lane & 31, hi = lane >> 5;
  int bid = blockIdx.x;
  int head = bid & 63;                    // bid&7 = head&7 -> stable XCD group per head
  int g = bid >> 6;                       // 0..7
  int s = (g < 4) ? (g*4 + wave) : (31 - (g - 4)*4 - wave);   // 64-row strip 0..31
  int bidx = head >> 4, hh = head & 15;
  const u16* qb = q  + (size_t)head * T_ * HD_;
  const u16* kb = k  + (size_t)head * T_ * HD_;
  const u16* vb = vt + (size_t)head * HD_ * T_;   // [HD][T]

  f32x16 zero16 = {0.f,0.f,0.f,0.f,0.f,0.f,0.f,0.f,0.f,0.f,0.f,0.f,0.f,0.f,0.f,0.f};

  int qr0 = s * 64;
  bf16x8 qfA[4], qfB[4];
  {
    const u16* qrowA = qb + (size_t)(qr0 + l31)*HD_ + hi*8;
    const u16* qrowB = qrowA + 32*HD_;
    #pragma unroll
    for (int i = 0; i < 4; ++i) { qfA[i] = *(const bf16x8*)(qrowA + 16*i);
                                  qfB[i] = *(const bf16x8*)(qrowB + 16*i); }
  }

  f32x16 oA0 = zero16, oA1 = zero16, oB0 = zero16, oB1 = zero16;
  float mrunA = -1e30f, lrunA = 0.f, mrunB = -1e30f, lrunB = 0.f;
  int qgA = qr0 + l31, qgB = qr0 + 32 + l31;

  auto halfstep = [&](bf16x8 (&qf)[4], f32x16 &od0, f32x16 &od1,
                      float &mrun, float &lrun, int qg, int kv0, bool domask,
                      bf16x8 (&kf)[8], bf16x8 (&vf)[8]) {
    f32x16 s0 = zero16, s1 = zero16;
    s0 = __builtin_amdgcn_mfma_f32_32x32x16_bf16(kf[0], qf[0], s0, 0, 0, 0);
    s1 = __builtin_amdgcn_mfma_f32_32x32x16_bf16(kf[4], qf[0], s1, 0, 0, 0);
    s0 = __builtin_amdgcn_mfma_f32_32x32x16_bf16(kf[1], qf[1], s0, 0, 0, 0);
    s1 = __builtin_amdgcn_mfma_f32_32x32x16_bf16(kf[5], qf[1], s1, 0, 0, 0);
    s0 = __builtin_amdgcn_mfma_f32_32x32x16_bf16(kf[2], qf[2], s0, 0, 0, 0);
    s1 = __builtin_amdgcn_mfma_f32_32x32x16_bf16(kf[6], qf[2], s1, 0, 0, 0);
    s0 = __builtin_amdgcn_mfma_f32_32x32x16_bf16(kf[3], qf[3], s0, 0, 0, 0);
    s1 = __builtin_amdgcn_mfma_f32_32x32x16_bf16(kf[7], qf[3], s1, 0, 0, 0);

    if (domask) {
      #pragma unroll
      for (int r = 0; r < 16; ++r) {
        int kl = (r & 3) + 8*(r >> 2) + 4*hi;
        if (kv0 + kl      > qg) s0[r] = -1e30f;
        if (kv0 + 32 + kl > qg) s1[r] = -1e30f;
      }
    }

    float t[16];
    #pragma unroll
    for (int i = 0; i < 16; ++i) t[i] = fmaxf(s0[i], s1[i]);
    #pragma unroll
    for (int off = 8; off > 0; off >>= 1)
      #pragma unroll
      for (int i = 0; i < 8; ++i)
        if (i < off) t[i] = fmaxf(t[i], t[i + off]);
    float pmax = xmaxf(t[0]);

    float mnew = fmaxf(mrun, pmax);
    float ex = EXP2(mrun - mnew);
    mrun = mnew;

    #pragma unroll
    for (int i = 0; i < 16; ++i) s0[i] = EXP2(s0[i] - mnew);
    #pragma unroll
    for (int i = 0; i < 16; ++i) s1[i] = EXP2(s1[i] - mnew);
    float u[16];
    #pragma unroll
    for (int i = 0; i < 16; ++i) u[i] = s0[i] + s1[i];
    #pragma unroll
    for (int off = 8; off > 0; off >>= 1)
      #pragma unroll
      for (int i = 0; i < 8; ++i)
        if (i < off) u[i] = u[i] + u[i + off];
    float rsum = xaddf(u[0]);
    lrun = lrun * ex + rsum;

    #pragma unroll
    for (int i = 0; i < 16; ++i) { od0[i] *= ex; od1[i] *= ex; }

    bf16x8 pf0, pf1, pf2, pf3;
    {
      u32 a0 = cvtpk(s0[0], s0[1]),   a1 = cvtpk(s0[2], s0[3]);
      u32 b0 = cvtpk(s0[4], s0[5]),   b1 = cvtpk(s0[6], s0[7]);
      plswap(a0, b0); plswap(a1, b1);
      u32 wa[4] = {a0, a1, b0, b1};
      __builtin_memcpy(&pf0, wa, 16);
    }
    {
      u32 a0 = cvtpk(s0[8], s0[9]),   a1 = cvtpk(s0[10], s0[11]);
      u32 b0 = cvtpk(s0[12], s0[13]), b1 = cvtpk(s0[14], s0[15]);
      plswap(a0, b0); plswap(a1, b1);
      u32 wa[4] = {a0, a1, b0, b1};
      __builtin_memcpy(&pf1, wa, 16);
    }
    {
      u32 a0 = cvtpk(s1[0], s1[1]),   a1 = cvtpk(s1[2], s1[3]);
      u32 b0 = cvtpk(s1[4], s1[5]),   b1 = cvtpk(s1[6], s1[7]);
      plswap(a0, b0); plswap(a1, b1);
      u32 wa[4] = {a0, a1, b0, b1};
      __builtin_memcpy(&pf2, wa, 16);
    }
    {
      u32 a0 = cvtpk(s1[8], s1[9]),   a1 = cvtpk(s1[10], s1[11]);
      u32 b0 = cvtpk(s1[12], s1[13]), b1 = cvtpk(s1[14], s1[15]);
      plswap(a0, b0); plswap(a1, b1);
      u32 wa[4] = {a0, a1, b0, b1};
      __builtin_memcpy(&pf3, wa, 16);
    }

    od0 = __builtin_amdgcn_mfma_f32_32x32x16_bf16(vf[0], pf0, od0, 0, 0, 0);
    od0 = __builtin_amdgcn_mfma_f32_32x32x16_bf16(vf[1], pf1, od0, 0, 0, 0);
    od0 = __builtin_amdgcn_mfma_f32_32x32x16_bf16(vf[2], pf2, od0, 0, 0, 0);
    od0 = __builtin_amdgcn_mfma_f32_32x32x16_bf16(vf[3], pf3, od0, 0, 0, 0);
    od1 = __builtin_amdgcn_mfma_f32_32x32x16_bf16(vf[4], pf0, od1, 0, 0, 0);
    od1 = __builtin_amdgcn_mfma_f32_32x32x16_bf16(vf[5], pf1, od1, 0, 0, 0);
    od1 = __builtin_amdgcn_mfma_f32_32x32x16_bf16(vf[6], pf2, od1, 0, 0, 0);
    od1 = __builtin_amdgcn_mfma_f32_32x32x16_bf16(vf[7], pf3, od1, 0, 0, 0);
  };

  for (int t = 0; t <= s; ++t) {
    int kv0 = t*64;
    bool last = (t == s);

    bf16x8 kf[8], vf[8];
    {
      const u16* krow = kb + (size_t)(kv0 + l31)*HD_ + hi*8;
      const u16* krow1 = krow + 32*HD_;
      #pragma unroll
      for (int i = 0; i < 4; ++i) { kf[i] = *(const bf16x8*)(krow + 16*i);
                                    kf[4+i] = *(const bf16x8*)(krow1 + 16*i); }
      const u16* vrow = vb + (size_t)l31*T_ + kv0 + hi*8;
      const u16* vrow1 = vrow + 32*T_;
      #pragma unroll
      for (int i = 0; i < 4; ++i) { vf[i] = *(const bf16x8*)(vrow + 16*i);
                                    vf[4+i] = *(const bf16x8*)(vrow1 + 16*i); }
    }

    halfstep(qfA, oA0, oA1, mrunA, lrunA, qgA, kv0, last, kf, vf);
    halfstep(qfB, oB0, oB1, mrunB, lrunB, qgB, kv0, last, kf, vf);
  }

  {
    float inv = 1.0f / lrunA;
    u16* yrow = y + ((size_t)(bidx*T_) + qr0 + l31)*C_ + hh*64;
    #pragma unroll
    for (int r = 0; r < 8; ++r) {
      int dp = ((2*r) & 3) + 8*(r >> 1) + 4*hi;
      *(u32*)(yrow + dp)      = cvtpk(oA0[2*r]*inv, oA0[2*r+1]*inv);
      *(u32*)(yrow + 32 + dp) = cvtpk(oA1[2*r]*inv, oA1[2*r+1]*inv);
    }
  }
  {
    float inv = 1.0f / lrunB;
    u16* yrow = y + ((size_t)(bidx*T_) + qr0 + 32 + l31)*C_ + hh*64;
    #pragma unroll
    for (int r = 0; r < 8; ++r) {
      int dp = ((2*r) & 3) + 8*(r >> 1) + 4*hi;
      *(u32*)(yrow + dp)      = cvtpk(oB0[2*r]*inv, oB0[2*r+1]*inv);
      *(u32*)(yrow + 32 + dp) = cvtpk(oB1[2*r]*inv, oB1[2*r+1]*inv);
    }
  }
}

extern "C" void kernel_launch(void* const* d_in, const int* in_sizes, int n_in,
                              void* d_out, int out_size, void* d_ws, size_t ws_size,
                              hipStream_t stream) {
  const float* x      = (const float*)d_in[0];
  const float* w_attn = (const float*)d_in[1];
  const float* b_attn = (const float*)d_in[2];
  const float* w_proj = (const float*)d_in[3];
  const float* b_proj = (const float*)d_in[4];

  char* ws = (char*)d_ws;
  size_t off = 0;
  auto walloc = [&](size_t bytes) -> void* {
    void* p = ws + off;
    off += (bytes + 255) & ~(size_t)255;
    return p;
  };
  u16* xbf  = (u16*)walloc((size_t)BT_ * C_ * 2);     // x as bf16; later reused as y
  u16* wat  = (u16*)walloc((size_t)C3_ * C_ * 2);     // w_attn^T bf16 [3C][C]
  u16* wpt  = (u16*)walloc((size_t)C_ * C_ * 2);      // w_proj^T bf16 [C][C]
  u16* qkv  = (u16*)walloc(3 * BHTD_ * 2);            // q,k [B,H,T,HD]; v^T [B,H,HD,T]
  u16* vtmp = (u16*)walloc(BHTD_ * 2);                // v untransposed [B,H,T,HD] (temp)
  u16* qp = qkv;
  u16* kp = qkv + BHTD_;
  u16* vp = qkv + 2*BHTD_;
  u16* ybf = xbf;   // alias: x consumed by GEMM1 before attention writes y

  k_cvt_bf16<<<(BT_*C_)/1024, 256, 0, stream>>>(x, xbf);
  k_transpose_bf16<<<dim3(C3_/32, C_/32), 256, 0, stream>>>(w_attn, wat, C_, C3_);
  k_transpose_bf16<<<dim3(C_/32, C_/32), 256, 0, stream>>>(w_proj, wpt, C_, C_);
  k_gemm<0><<<dim3(C3_/128, BT_/128), 256, 0, stream>>>(xbf, wat, b_attn, (void*)qkv, (void*)vtmp, C_);
  k_transpose_v<<<dim3(T_/64, B_*H_), 256, 0, stream>>>(vtmp, vp);
  k_attn<<<dim3(512), 256, 0, stream>>>(qp, kp, vp, ybf);
  k_gemm<1><<<dim3(C_/128, BT_/128), 256, 0, stream>>>(ybf, wpt, b_proj, d_out, nullptr, C_);
}